// Round 3
// baseline (405.222 us; speedup 1.0000x reference)
//
#include <hip/hip_runtime.h>
#include <hip/hip_bf16.h>

#define LL 9216            // 96*96
#define TOT 36864          // 4*LL
#define CHK 144
#define NSEG 144
#define EPS_N 5e-5f

typedef __bf16 bf16x8 __attribute__((ext_vector_type(8)));
typedef float f32x4 __attribute__((ext_vector_type(4)));

__device__ __forceinline__ float dot4(float4 a, float4 b) {
    return a.x*b.x + a.y*b.y + a.z*b.z + a.w*b.w;
}
__device__ __forceinline__ unsigned short f2bf(float f) {
    __hip_bfloat16 h = __float2bfloat16(f);
    return *reinterpret_cast<unsigned short*>(&h);
}
__device__ __forceinline__ float bf2f(unsigned short u) {
    return __uint_as_float(((unsigned int)u) << 16);
}

// ---------------- K1: xe conv + LSH codes + bf16 xeb/xnb + weight prep -----------
// blocks 0..287: conv 8x8 tile + codes; blocks 288..575: weight prep. 46 KB LDS.
__global__ __launch_bounds__(256) void k_front(
    const float* __restrict__ x, const float* __restrict__ wm,
    const float* __restrict__ bm, const float* __restrict__ rot,
    unsigned short* __restrict__ xeb, unsigned short* __restrict__ xnb,
    unsigned char* __restrict__ codes,
    const float* __restrict__ fc1w, const float* __restrict__ fc2w,
    const float* __restrict__ wa, const float* __restrict__ wf,
    unsigned short* __restrict__ w1bf, unsigned short* __restrict__ w2bf,
    unsigned short* __restrict__ wpack)
{
    int tid = threadIdx.x;
    if (blockIdx.x >= 288) {   // ---- weight prep ----
        int i = (blockIdx.x - 288) * 256 + tid;
        if (i < 144 * 64) w1bf[i] = f2bf(fc1w[i]);
        if (i < 144 * 160) {
            int r = i / 160, c = i - r * 160;
            w2bf[i] = (c < 144) ? f2bf(fc2w[r * 144 + c]) : 0;
        }
        if (i < 128 * 576) {
            int o = i / 576, kk = i - o * 576;
            int dydx = kk >> 6, c = kk & 63;
            const float* src = (o < 64) ? wa : wf;
            wpack[i] = f2bf(src[(o & 63) * 576 + c * 9 + dydx]);
        }
        return;
    }
    __shared__ float xl[6400];       // [64][10][10] halo tile (25.6 KB)
    __shared__ float rotT[4096];     // [h*64+i][16]          (16 KB)
    __shared__ float xsp[64 * 20];   // [pos][ch pad20]       (5 KB)
    int b = blockIdx.x;
    int n = b / 144, tile = b % 144;
    int ty0 = (tile / 12) * 8, tx0 = (tile % 12) * 8;
    for (int li = tid; li < 6400; li += 256) {
        int c = li / 100, s = li % 100;
        int yy = s / 10, xx = s % 10;
        int gy = ty0 + yy - 1, gx = tx0 + xx - 1;
        float v = 0.f;
        if ((unsigned)gy < 96u && (unsigned)gx < 96u)
            v = x[((n * 64 + c) * 96 + gy) * 96 + gx];
        xl[li] = v;
    }
    for (int e = tid; e < 4096; e += 256) {
        int f = e >> 8, r = e & 255;
        rotT[r * 16 + f] = rot[f * 256 + r];   // rot is (16,4,64)
    }
    __syncthreads();
    int p = tid & 63, og = tid >> 6;
    int row = p >> 3, col = p & 7;
    int ogs = __builtin_amdgcn_readfirstlane(og);   // wave-uniform -> s_load path
    const float* wb = wm + (size_t)ogs * 4 * 576;
    float acc0 = 0.f, acc1 = 0.f, acc2 = 0.f, acc3 = 0.f;
    for (int c = 0; c < 64; ++c) {
        float xp[9];
        int base = c * 100 + row * 10 + col;
        #pragma unroll
        for (int dy = 0; dy < 3; ++dy)
            #pragma unroll
            for (int dx = 0; dx < 3; ++dx)
                xp[dy * 3 + dx] = xl[base + dy * 10 + dx];
        const float* w0 = wb + c * 9;
        #pragma unroll
        for (int u = 0; u < 9; ++u) {
            acc0 += w0[u]        * xp[u];
            acc1 += w0[576 + u]  * xp[u];
            acc2 += w0[1152 + u] * xp[u];
            acc3 += w0[1728 + u] * xp[u];
        }
    }
    int o = ogs * 4;
    float v0 = acc0 + bm[o + 0]; v0 = v0 > 0.f ? v0 : 0.f;
    float v1 = acc1 + bm[o + 1]; v1 = v1 > 0.f ? v1 : 0.f;
    float v2 = acc2 + bm[o + 2]; v2 = v2 > 0.f ? v2 : 0.f;
    float v3 = acc3 + bm[o + 3]; v3 = v3 > 0.f ? v3 : 0.f;
    size_t t = (size_t)n * LL + (ty0 + row) * 96 + tx0 + col;
    unsigned short pk[4] = {f2bf(v0), f2bf(v1), f2bf(v2), f2bf(v3)};
    *(uint2*)(xeb + t * 16 + o) = *(uint2*)pk;
    *(float4*)(xsp + p * 20 + o) = make_float4(v0, v1, v2, v3);
    __syncthreads();
    // ---- codes phase: thread = (pos = tid&63, h = tid>>6) ----
    int pos = tid & 63, h = tid >> 6;
    int prow = pos >> 3, pcol = pos & 7;
    size_t tc = (size_t)n * LL + (ty0 + prow) * 96 + tx0 + pcol;
    float4 q0 = *(float4*)(xsp + pos * 20 + 0);
    float4 q1 = *(float4*)(xsp + pos * 20 + 4);
    float4 q2 = *(float4*)(xsp + pos * 20 + 8);
    float4 q3 = *(float4*)(xsp + pos * 20 + 12);
    if (h == 0) {
        float nn = dot4(q0,q0) + dot4(q1,q1) + dot4(q2,q2) + dot4(q3,q3);
        float s = fmaxf(sqrtf(nn), EPS_N);
        float inv = 1.f / s;
        unsigned short pn[16];
        pn[0]=f2bf(q0.x*inv);  pn[1]=f2bf(q0.y*inv);  pn[2]=f2bf(q0.z*inv);  pn[3]=f2bf(q0.w*inv);
        pn[4]=f2bf(q1.x*inv);  pn[5]=f2bf(q1.y*inv);  pn[6]=f2bf(q1.z*inv);  pn[7]=f2bf(q1.w*inv);
        pn[8]=f2bf(q2.x*inv);  pn[9]=f2bf(q2.y*inv);  pn[10]=f2bf(q2.z*inv); pn[11]=f2bf(q2.w*inv);
        pn[12]=f2bf(q3.x*inv); pn[13]=f2bf(q3.y*inv); pn[14]=f2bf(q3.z*inv); pn[15]=f2bf(q3.w*inv);
        *(uint4*)(xnb + tc * 16)     = ((uint4*)pn)[0];
        *(uint4*)(xnb + tc * 16 + 8) = ((uint4*)pn)[1];
    }
    float best = -1e30f; int bi = 0;
    const float* rp = rotT + h * 1024;
    for (int i = 0; i < 64; ++i) {
        const float4* r4 = (const float4*)(rp + i * 16);
        float v = dot4(q0, r4[0]) + dot4(q1, r4[1]) + dot4(q2, r4[2]) + dot4(q3, r4[3]);
        if (v > best) { best = v; bi = i; }   // strict > = first max (jnp.argmax)
    }
    codes[(size_t)n * TOT + h * LL + (tc - (size_t)n * LL)] = (unsigned char)(h * 64 + bi);
}

// ---------------- K2: ye/fe conv bf16 MFMA + fused hist --------------------------
// R13: FC GEMMs moved INTO k_attn (recompute-from-fe kills the 288B/slot fs
// stream that was 63MB of k_attn's 89MB fetch). This kernel now just writes the
// two conv outputs (ye -> yeb, fe -> feb) densely.
__global__ __launch_bounds__(256) void k_convbf_fc(
    const float* __restrict__ x, const unsigned short* __restrict__ wpack,
    const float* __restrict__ ba, const float* __restrict__ bfb,
    unsigned short* __restrict__ yeb, unsigned short* __restrict__ feb,
    const unsigned char* __restrict__ codes, int* __restrict__ hist)
{
    __shared__ unsigned short xt[3 * 50 * 72];   // input halo strip, ch-inner
    __shared__ int lh[256];
    int tid = threadIdx.x;
    if (blockIdx.x >= 384) {   // ---- histogram branch ----
        int b2 = blockIdx.x - 384;
        int n = b2 / NSEG, seg = b2 % NSEG;
        lh[tid] = 0;
        __syncthreads();
        int code = codes[(size_t)n * TOT + seg * 256 + tid];
        atomicAdd(&lh[code], 1);
        __syncthreads();
        hist[((size_t)n * 256 + tid) * NSEG + seg] = lh[tid];
        return;
    }
    int b = blockIdx.x;
    int n = b / 192, rem = b % 192;
    int y = rem >> 1, strip = rem & 1;
    int x0 = strip * 48;
    for (int e = tid; e < 9600; e += 256) {
        int r = e / 3200, r2 = e - r * 3200;
        int c = r2 / 50, j = r2 - c * 50;
        int gy = y - 1 + r, gx = x0 - 1 + j;
        float v = 0.f;
        if ((unsigned)gy < 96u && (unsigned)gx < 96u)
            v = x[((n * 64 + c) * 96 + gy) * 96 + gx];
        xt[(r * 50 + j) * 72 + c] = f2bf(v);
    }
    __syncthreads();
    int wave = tid >> 6, lane = tid & 63;
    int n16 = lane & 15, quad = lane >> 4;
    f32x4 acc[2][3];
    #pragma unroll
    for (int mi = 0; mi < 2; ++mi)
        #pragma unroll
        for (int nt = 0; nt < 3; ++nt) acc[mi][nt] = (f32x4){0.f, 0.f, 0.f, 0.f};
    #pragma unroll
    for (int s = 0; s < 18; ++s) {
        int dydx = s >> 1, half = s & 1;
        int dy = dydx / 3, dxm = dydx - dy * 3;
        bf16x8 B[3];
        #pragma unroll
        for (int nt = 0; nt < 3; ++nt) {
            int j = nt * 16 + n16 + dxm;
            B[nt] = *(bf16x8*)(xt + (dy * 50 + j) * 72 + half * 32 + quad * 8);
        }
        #pragma unroll
        for (int mi = 0; mi < 2; ++mi) {
            int o = (wave * 2 + mi) * 16 + n16;
            bf16x8 A = *(const bf16x8*)(wpack + o * 576 + dydx * 64 + half * 32 + quad * 8);
            #pragma unroll
            for (int nt = 0; nt < 3; ++nt)
                acc[mi][nt] = __builtin_amdgcn_mfma_f32_16x16x32_bf16(A, B[nt], acc[mi][nt], 0, 0, 0);
        }
    }
    #pragma unroll
    for (int mi = 0; mi < 2; ++mi) {
        int mt = wave * 2 + mi;
        int obase = mt * 16 + quad * 4;          // 0..124, multiple of 4
        float4 b4 = (mt < 4) ? *(const float4*)(ba + obase)
                             : *(const float4*)(bfb + obase - 64);
        #pragma unroll
        for (int nt = 0; nt < 3; ++nt) {
            int j = nt * 16 + n16;               // local position 0..47
            unsigned short pk[4];
            float v0 = acc[mi][nt][0] + b4.x; pk[0] = f2bf(v0 > 0.f ? v0 : 0.f);
            float v1 = acc[mi][nt][1] + b4.y; pk[1] = f2bf(v1 > 0.f ? v1 : 0.f);
            float v2 = acc[mi][nt][2] + b4.z; pk[2] = f2bf(v2 > 0.f ? v2 : 0.f);
            float v3 = acc[mi][nt][3] + b4.w; pk[3] = f2bf(v3 > 0.f ? v3 : 0.f);
            size_t t = (size_t)n * LL + y * 96 + x0 + j;
            if (mt < 4) *(uint2*)(yeb + t * 64 + obase)        = *(uint2*)pk;
            else        *(uint2*)(feb + t * 64 + (obase - 64)) = *(uint2*)pk;
        }
    }
}

// ---------------- K3: counting sort scan + place --------------------------------
__global__ void k_scan(int* __restrict__ hist)
{
    __shared__ int sc[256];
    int n = blockIdx.x, bin = threadIdx.x;
    int* hp = hist + ((size_t)n * 256 + bin) * NSEG;
    int4 buf[36];
    int4* hp4 = (int4*)hp;
    #pragma unroll
    for (int q = 0; q < 36; ++q) buf[q] = hp4[q];
    int running = 0;
    #pragma unroll
    for (int q = 0; q < 36; ++q) {
        int t0 = buf[q].x; buf[q].x = running; running += t0;
        int t1 = buf[q].y; buf[q].y = running; running += t1;
        int t2 = buf[q].z; buf[q].z = running; running += t2;
        int t3 = buf[q].w; buf[q].w = running; running += t3;
    }
    sc[bin] = running;
    __syncthreads();
    for (int off = 1; off < 256; off <<= 1) {
        int v = sc[bin];
        int u = (bin >= off) ? sc[bin - off] : 0;
        __syncthreads();
        sc[bin] = v + u;
        __syncthreads();
    }
    int bs = sc[bin] - running;   // exclusive prefix over bins
    #pragma unroll
    for (int q = 0; q < 36; ++q) {
        buf[q].x += bs; buf[q].y += bs; buf[q].z += bs; buf[q].w += bs;
        hp4[q] = buf[q];
    }
}

__global__ __launch_bounds__(256) void k_place(
    const unsigned char* __restrict__ codes, const int* __restrict__ hist,
    int* __restrict__ idx)
{
    __shared__ unsigned char cl[256];
    int b = blockIdx.x, n = b / NSEG, seg = b % NSEG;
    int tid = threadIdx.x;
    int my = codes[(size_t)n * TOT + seg * 256 + tid];
    cl[tid] = (unsigned char)my;
    __syncthreads();
    int rank = 0;
    for (int j = 0; j < tid; ++j) rank += (cl[j] == my);
    int pos = hist[((size_t)n * 256 + my) * NSEG + seg] + rank;
    idx[(size_t)n * TOT + pos] = seg * 256 + tid;
}

// ---------------- K3b: materialize sorted operand streams -----------------------
// Sorts q/k/v/fe embeddings into bucket order once (scattered reads, dense
// writes) so k_attn sees only contiguous spans. fes (128B/slot) replaces the
// old fs (288B/slot): per-(n,h) resident set 2.65MB now fits one XCD L2.
__global__ __launch_bounds__(256) void k_gather(
    const int* __restrict__ idx, const unsigned short* __restrict__ xeb,
    const unsigned short* __restrict__ xnb, const unsigned short* __restrict__ yeb,
    const unsigned short* __restrict__ feb,
    unsigned short* __restrict__ qs, unsigned short* __restrict__ ks,
    unsigned short* __restrict__ vs, unsigned short* __restrict__ fes,
    int* __restrict__ undo)
{
    __shared__ int tl[64];
    int b = blockIdx.x;
    int nh = b / 144, grp = b % 144;            // nh = n*4+h, 64 sorted slots per block
    int n = nh >> 2, h = nh & 3;
    size_t sbase = (size_t)nh * LL + grp * 64;
    size_t nL = (size_t)n * LL;
    int tid = threadIdx.x;
    if (tid < 64) {
        int t = idx[(size_t)n * TOT + h * LL + grp * 64 + tid] - h * LL;
        tl[tid] = t;
        undo[(size_t)nh * LL + t] = grp * 64 + tid;
    }
    __syncthreads();
    // qs/ks: 2x16B per slot
    for (int e = tid; e < 128; e += 256) {
        int s = e >> 1, c = e & 1;
        size_t src = (nL + tl[s]) * 16 + c * 8;
        *(uint4*)(qs + (sbase + s) * 16 + c * 8) = *(const uint4*)(xeb + src);
        *(uint4*)(ks + (sbase + s) * 16 + c * 8) = *(const uint4*)(xnb + src);
    }
    // vs / fes: 8x16B per slot each
    for (int e = tid; e < 512; e += 256) {
        int s = e >> 3, c = e & 7;
        *(uint4*)(vs + (sbase + s) * 64 + c * 8) =
            *(const uint4*)(yeb + (nL + tl[s]) * 64 + c * 8);
        *(uint4*)(fes + (sbase + s) * 64 + c * 8) =
            *(const uint4*)(feb + (nL + tl[s]) * 64 + c * 8);
    }
}

// ---------------- K4: bucketed attention with in-kernel FC recompute ------------
// R13. The fs (fc-score) stream was 63MB of an 89MB fetch and pushed the
// per-(n,h) set past L2. Now k_attn recomputes it: per key-tile,
//   hid = relu(fes @ fc1^T + b1)   (MFMA, staged to shared hidT LDS)
//   raw = b2 + fc2 @ hid^T         (MFMA C-init, K=160; w2bf zero-padded)
//   raw += Q K^T                   (MFMA)
// then online softmax + PV as before. V is staged to ONE shared swizzled LDS
// copy (was per-wave x4). Streams per (n,h): ks .29 + vs 1.18 + fes 1.18 =
// 2.65MB -> L2-resident; window re-reads become hits. 2 barriers/tile (proven
// harmless R0 vs R1). Per-tile frag reloads keep VGPR <= 256 (2 blocks/CU).
__global__ __launch_bounds__(256, 2) void k_attn(
    const unsigned short* __restrict__ qs, const unsigned short* __restrict__ ks,
    const unsigned short* __restrict__ vs, const unsigned short* __restrict__ fes,
    const unsigned short* __restrict__ w1bf, const float* __restrict__ fc1_b,
    const unsigned short* __restrict__ w2bf, const float* __restrict__ fc2_b,
    unsigned short* __restrict__ rets, float* __restrict__ bscs)
{
    __shared__ __align__(16) unsigned short Vt[64 * 64];      // shared V^T swizzled (8 KB)
    __shared__ __align__(16) unsigned short Pw[4][48 * 56];   // per-wave P (21 KB)
    __shared__ __align__(16) unsigned short hidT[48 * 152];   // hid [j][m2 pad152] (14.25 KB)

    int B = blockIdx.x;
    int b = ((B & 7) << 6) | (B >> 3);           // XCD swizzle (512 = 8 x 64, bijective)
    int n = b >> 8, rem = b & 255;
    int h = rem >> 6, k = rem & 63;
    int tid = threadIdx.x;
    int lane = tid & 63, wv = tid >> 6;
    int n16 = lane & 15, quad = lane >> 4;
    int nmt = (wv == 0) ? 3 : 2;                 // query/m2 tiles owned: {wv, wv+4, wv==0? 8}

    size_t hL = (size_t)(n * 4 + h) * LL;
    size_t sp0 = hL + (size_t)k * 144;
    size_t sp1 = hL + (size_t)((k + 63) & 63) * 144;
    size_t sp2 = hL + (size_t)((k + 1) & 63) * 144;

    unsigned short* Pp = &Pw[wv][0];
    int su = tid & 7, jp = tid >> 3;             // Vt staging role (threads 0..191)

    // zero Vt pad slots j=48..63 (PV kk=1 quads 2,3 read them)
    for (int e = tid; e < 512; e += 256) {
        int c = e >> 3, j = 48 + (e & 7) * 2;
        int bp = ((j >> 3) ^ (c >> 3) ^ (((c >> 2) & 1) << 2)) & 7;
        *(unsigned int*)(Vt + c * 64 + bp * 8 + (j & 7)) = 0;
    }
    // zero hidT pad cols m2=144..159 (read by fc-mfma kk2=4; avoid 0*NaN)
    for (int e = tid; e < 384; e += 256) {
        int r = e >> 3;
        *(unsigned int*)(hidT + r * 152 + 144 + (e & 7) * 2) = 0;
    }

    // query A-fragments: K=16 real, padded to 32 via zero quads>=2
    bf16x8 afragQ[3] = {};
    #pragma unroll
    for (int mi = 0; mi < 3; ++mi)
        if (mi < nmt && quad < 2)
            afragQ[mi] = *(const bf16x8*)(qs + (sp0 + (wv + mi * 4) * 16 + n16) * 16 + quad * 8);

    f32x4 acc[3][4];                             // [mi][ct]: rows mi, channels ct*16+n16
    float rm[3][4], rl[3][4];
    #pragma unroll
    for (int mi = 0; mi < 3; ++mi) {
        #pragma unroll
        for (int ct = 0; ct < 4; ++ct) acc[mi][ct] = (f32x4){0.f, 0.f, 0.f, 0.f};
        #pragma unroll
        for (int r = 0; r < 4; ++r) { rm[mi][r] = -1e30f; rl[mi][r] = 0.f; }
    }

    uint4 vaA, vbA, vaB, vbB;
    bf16x8 ksA[3] = {}, ksB[3] = {};
    bf16x8 feA[3][2], feB[3][2];

// issue tile TT's loads (dense spans)
#define ATTN_LOAD(TT, VA, VB, KS, FE) do {                                           \
    int reg_ = (TT) / 3;                                                             \
    size_t sb_ = (reg_ == 0 ? sp0 : (reg_ == 1 ? sp1 : sp2)) + ((TT) % 3) * 48;      \
    if (tid < 192) {                                                                 \
        VA = *(const uint4*)(vs + (sb_ + jp * 2) * 64 + su * 8);                     \
        VB = *(const uint4*)(vs + (sb_ + jp * 2 + 1) * 64 + su * 8);                 \
    }                                                                                \
    if (quad < 2) {                                                                  \
        KS[0] = *(const bf16x8*)(ks + (sb_ + n16) * 16 + quad * 8);                  \
        KS[1] = *(const bf16x8*)(ks + (sb_ + 16 + n16) * 16 + quad * 8);             \
        KS[2] = *(const bf16x8*)(ks + (sb_ + 32 + n16) * 16 + quad * 8);             \
    }                                                                                \
    _Pragma("unroll")                                                                \
    for (int lj_ = 0; lj_ < 3; ++lj_)                                                \
        _Pragma("unroll")                                                            \
        for (int lk_ = 0; lk_ < 2; ++lk_)                                            \
            FE[lj_][lk_] = *(const bf16x8*)(fes + (sb_ + lj_ * 16 + n16) * 64        \
                                            + lk_ * 32 + quad * 8);                  \
} while (0)

// one key-tile iteration
#define ATTN_ITER(TT, VA, VB, KS, FE, NVA, NVB, NKS, NFE) do {                       \
    /* hid = relu(fes @ fc1^T + b1) -> hidT (D cols = j via n16) */                  \
    _Pragma("unroll")                                                                \
    for (int mi_ = 0; mi_ < 3; ++mi_) {                                              \
        if (mi_ >= nmt) continue;                                                    \
        int qr_ = (wv + mi_ * 4) * 16;                                               \
        bf16x8 w10_ = *(const bf16x8*)(w1bf + (qr_ + n16) * 64 + quad * 8);          \
        bf16x8 w11_ = *(const bf16x8*)(w1bf + (qr_ + n16) * 64 + 32 + quad * 8);     \
        float4 b1_ = *(const float4*)(fc1_b + qr_ + quad * 4);                       \
        _Pragma("unroll")                                                            \
        for (int jt_ = 0; jt_ < 3; ++jt_) {                                          \
            f32x4 hd_ = {b1_.x, b1_.y, b1_.z, b1_.w};                                \
            hd_ = __builtin_amdgcn_mfma_f32_16x16x32_bf16(w10_, FE[jt_][0], hd_, 0, 0, 0); \
            hd_ = __builtin_amdgcn_mfma_f32_16x16x32_bf16(w11_, FE[jt_][1], hd_, 0, 0, 0); \
            float h0_ = hd_[0] > 0.f ? hd_[0] : 0.f;                                 \
            float h1_ = hd_[1] > 0.f ? hd_[1] : 0.f;                                 \
            float h2_ = hd_[2] > 0.f ? hd_[2] : 0.f;                                 \
            float h3_ = hd_[3] > 0.f ? hd_[3] : 0.f;                                 \
            unsigned int u0_ = (unsigned int)f2bf(h0_) | ((unsigned int)f2bf(h1_) << 16); \
            unsigned int u1_ = (unsigned int)f2bf(h2_) | ((unsigned int)f2bf(h3_) << 16); \
            unsigned short* hp_ = hidT + (jt_ * 16 + n16) * 152 + qr_ + quad * 4;    \
            *(unsigned int*)(hp_) = u0_;                                             \
            *(unsigned int*)(hp_ + 2) = u1_;                                         \
        }                                                                            \
    }                                                                                \
    /* stage V(T) regs -> shared swizzled Vt (threads 0..191) */                     \
    if (tid < 192) {                                                                 \
        int j0_ = jp * 2;                                                            \
        const unsigned short* pa_ = (const unsigned short*)&VA;                      \
        const unsigned short* pb_ = (const unsigned short*)&VB;                      \
        int B0_ = j0_ >> 3, jlo_ = j0_ & 7;                                          \
        _Pragma("unroll")                                                            \
        for (int ci_ = 0; ci_ < 8; ++ci_) {                                          \
            int c_ = su * 8 + ci_;                                                   \
            int bp_ = (B0_ ^ (c_ >> 3) ^ (((c_ >> 2) & 1) << 2)) & 7;                \
            *(unsigned int*)(Vt + c_ * 64 + bp_ * 8 + jlo_) =                        \
                (unsigned int)pa_[ci_] | ((unsigned int)pb_[ci_] << 16);             \
        }                                                                            \
    }                                                                                \
    if ((TT) < 8) ATTN_LOAD((TT) + 1, NVA, NVB, NKS, NFE);                           \
    __syncthreads();   /* hidT + Vt ready */                                         \
    /* raw = b2 + fc2 @ hid^T + Q K^T */                                             \
    f32x4 rawc_[3][3];                                                               \
    _Pragma("unroll")                                                                \
    for (int mi_ = 0; mi_ < 3; ++mi_) {                                              \
        if (mi_ >= nmt) continue;                                                    \
        float4 b2_ = *(const float4*)(fc2_b + (wv + mi_ * 4) * 16 + quad * 4);       \
        _Pragma("unroll")                                                            \
        for (int jt_ = 0; jt_ < 3; ++jt_)                                            \
            rawc_[mi_][jt_] = (f32x4){b2_.x, b2_.y, b2_.z, b2_.w};                   \
    }                                                                                \
    _Pragma("unroll")                                                                \
    for (int jt_ = 0; jt_ < 3; ++jt_) {                                              \
        bf16x8 bp_[5];                                                               \
        _Pragma("unroll")                                                            \
        for (int kk_ = 0; kk_ < 5; ++kk_)                                            \
            bp_[kk_] = *(const bf16x8*)(hidT + (jt_ * 16 + n16) * 152                \
                                        + kk_ * 32 + quad * 8);                      \
        _Pragma("unroll")                                                            \
        for (int mi_ = 0; mi_ < 3; ++mi_) {                                          \
            if (mi_ >= nmt) continue;                                                \
            const unsigned short* a2p_ = w2bf + ((wv + mi_ * 4) * 16 + n16) * 160 + quad * 8; \
            _Pragma("unroll")                                                        \
            for (int kk_ = 0; kk_ < 5; ++kk_)                                        \
                rawc_[mi_][jt_] = __builtin_amdgcn_mfma_f32_16x16x32_bf16(           \
                    *(const bf16x8*)(a2p_ + kk_ * 32), bp_[kk_], rawc_[mi_][jt_], 0, 0, 0); \
        }                                                                            \
    }                                                                                \
    _Pragma("unroll")                                                                \
    for (int mi_ = 0; mi_ < 3; ++mi_) {                                              \
        if (mi_ >= nmt) continue;                                                    \
        rawc_[mi_][0] = __builtin_amdgcn_mfma_f32_16x16x32_bf16(afragQ[mi_], KS[0], rawc_[mi_][0], 0, 0, 0); \
        rawc_[mi_][1] = __builtin_amdgcn_mfma_f32_16x16x32_bf16(afragQ[mi_], KS[1], rawc_[mi_][1], 0, 0, 0); \
        rawc_[mi_][2] = __builtin_amdgcn_mfma_f32_16x16x32_bf16(afragQ[mi_], KS[2], rawc_[mi_][2], 0, 0, 0); \
    }                                                                                \
    /* online softmax (per-wave rows; reduce over n16=j) */                          \
    _Pragma("unroll")                                                                \
    for (int mi_ = 0; mi_ < 3; ++mi_) {                                              \
        if (mi_ >= nmt) continue;                                                    \
        _Pragma("unroll")                                                            \
        for (int r_ = 0; r_ < 4; ++r_) {                                             \
            float v0_ = rawc_[mi_][0][r_], v1_ = rawc_[mi_][1][r_], v2_ = rawc_[mi_][2][r_]; \
            float mm_ = fmaxf(fmaxf(v0_, v1_), v2_);                                 \
            mm_ = fmaxf(mm_, __shfl_xor(mm_, 1, 16));                                \
            mm_ = fmaxf(mm_, __shfl_xor(mm_, 2, 16));                                \
            mm_ = fmaxf(mm_, __shfl_xor(mm_, 4, 16));                                \
            mm_ = fmaxf(mm_, __shfl_xor(mm_, 8, 16));                                \
            float mn_ = fmaxf(rm[mi_][r_], mm_);                                     \
            float a_ = __expf(rm[mi_][r_] - mn_);                                    \
            float s0_ = __expf(v0_ - mn_), s1_ = __expf(v1_ - mn_), s2_ = __expf(v2_ - mn_); \
            float ss_ = s0_ + s1_ + s2_;                                             \
            ss_ += __shfl_xor(ss_, 1, 16);                                           \
            ss_ += __shfl_xor(ss_, 2, 16);                                           \
            ss_ += __shfl_xor(ss_, 4, 16);                                           \
            ss_ += __shfl_xor(ss_, 8, 16);                                           \
            rl[mi_][r_] = rl[mi_][r_] * a_ + ss_;                                    \
            rm[mi_][r_] = mn_;                                                       \
            acc[mi_][0][r_] *= a_; acc[mi_][1][r_] *= a_;                            \
            acc[mi_][2][r_] *= a_; acc[mi_][3][r_] *= a_;                            \
            int rw_ = mi_ * 16 + quad * 4 + r_;                                      \
            Pp[rw_ * 56 +      n16] = f2bf(s0_);                                     \
            Pp[rw_ * 56 + 16 + n16] = f2bf(s1_);                                     \
            Pp[rw_ * 56 + 32 + n16] = f2bf(s2_);                                     \
        }                                                                            \
    }                                                                                \
    /* PV: shared Vt, per-wave P */                                                  \
    _Pragma("unroll")                                                                \
    for (int kk_ = 0; kk_ < 2; ++kk_) {                                              \
        bf16x8 Bv_[4];                                                               \
        _Pragma("unroll")                                                            \
        for (int ct_ = 0; ct_ < 4; ++ct_) {                                          \
            int c_ = ct_ * 16 + n16;                                                 \
            int bp_ = ((kk_ * 4 + quad) ^ (c_ >> 3) ^ (((c_ >> 2) & 1) << 2)) & 7;   \
            Bv_[ct_] = *(const bf16x8*)(Vt + c_ * 64 + bp_ * 8);                     \
        }                                                                            \
        _Pragma("unroll")                                                            \
        for (int mi_ = 0; mi_ < 3; ++mi_) {                                          \
            if (mi_ >= nmt) continue;                                                \
            bf16x8 Ap_ = {};                                                         \
            if (kk_ == 0)                                                            \
                Ap_ = *(const bf16x8*)(Pp + (mi_ * 16 + n16) * 56 + quad * 8);       \
            else if (quad < 2)                                                       \
                Ap_ = *(const bf16x8*)(Pp + (mi_ * 16 + n16) * 56 + 32 + quad * 8);  \
            _Pragma("unroll")                                                        \
            for (int ct_ = 0; ct_ < 4; ++ct_)                                        \
                acc[mi_][ct_] = __builtin_amdgcn_mfma_f32_16x16x32_bf16(Ap_, Bv_[ct_], acc[mi_][ct_], 0, 0, 0); \
        }                                                                            \
    }                                                                                \
    __syncthreads();   /* hidT/Vt consumed; next tile may overwrite */               \
} while (0)

    ATTN_LOAD(0, vaA, vbA, ksA, feA);
    for (int T2 = 0; T2 < 8; T2 += 2) {
        ATTN_ITER(T2,     vaA, vbA, ksA, feA, vaB, vbB, ksB, feB);
        ATTN_ITER(T2 + 1, vaB, vbB, ksB, feB, vaA, vbA, ksA, feA);
    }
    ATTN_ITER(8, vaA, vbA, ksA, feA, vaB, vbB, ksB, feB);

#undef ATTN_ITER
#undef ATTN_LOAD

    // ---- epilogue: dense writes in sorted order ----
    if (n16 == 0) {
        #pragma unroll
        for (int mi = 0; mi < 3; ++mi) {
            if (mi >= nmt) continue;
            int rowb = (wv + mi * 4) * 16 + quad * 4;
            #pragma unroll
            for (int r = 0; r < 4; ++r)
                bscs[sp0 + rowb + r] = rm[mi][r] + __logf(rl[mi][r]);
        }
    }
    #pragma unroll
    for (int mi = 0; mi < 3; ++mi) {
        if (mi >= nmt) continue;
        int rowb = (wv + mi * 4) * 16 + quad * 4;
        #pragma unroll
        for (int r = 0; r < 4; ++r) {
            float inv = 1.f / rl[mi][r];
            #pragma unroll
            for (int ct = 0; ct < 4; ++ct)
                rets[(sp0 + rowb + r) * 64 + ct * 16 + n16] = f2bf(acc[mi][ct][r] * inv);
        }
    }
}

// ---------------- K5: softmax over rounds + residual, NCHW output ----------------
// Reads sorted rets/bscs through the undo permutation (scattered 128B-row reads).
__global__ __launch_bounds__(256) void k_final(
    const unsigned short* __restrict__ rets, const float* __restrict__ bscs,
    const int* __restrict__ undo, const float* __restrict__ x,
    float* __restrict__ out)
{
    __shared__ float pr[4][64];
    __shared__ int us[4][64];
    __shared__ float accl[64 * 65];
    int b = blockIdx.x, n = b / 144;
    int t0 = (b % 144) * 64;
    int tid = threadIdx.x;
    {
        int h = tid >> 6, tt = tid & 63;
        us[h][tt] = undo[((size_t)n * 4 + h) * LL + t0 + tt];
    }
    __syncthreads();
    if (tid < 64) {
        float b0 = bscs[((size_t)n * 4 + 0) * LL + us[0][tid]];
        float b1 = bscs[((size_t)n * 4 + 1) * LL + us[1][tid]];
        float b2 = bscs[((size_t)n * 4 + 2) * LL + us[2][tid]];
        float b3 = bscs[((size_t)n * 4 + 3) * LL + us[3][tid]];
        float mx = fmaxf(fmaxf(b0, b1), fmaxf(b2, b3));
        float e0 = __expf(b0-mx), e1 = __expf(b1-mx), e2 = __expf(b2-mx), e3 = __expf(b3-mx);
        float inv = 1.f / (e0 + e1 + e2 + e3);
        pr[0][tid] = e0*inv; pr[1][tid] = e1*inv; pr[2][tid] = e2*inv; pr[3][tid] = e3*inv;
    }
    __syncthreads();
    int cc = tid & 63, tt4 = tid >> 6;
    #pragma unroll
    for (int q = 0; q < 16; ++q) {
        int tt = tt4 + 4*q;
        float v = 0.f;
        #pragma unroll
        for (int h2 = 0; h2 < 4; ++h2)
            v += bf2f(rets[(((size_t)n*4 + h2)*LL + us[h2][tt])*64 + cc]) * pr[h2][tt];
        accl[cc*65 + tt] = v;
    }
    __syncthreads();
    int tt = tid & 63, c4 = tid >> 6;
    #pragma unroll
    for (int q = 0; q < 16; ++q) {
        int ch = c4 + 4*q;
        size_t o = ((size_t)n*64 + ch)*LL + t0 + tt;
        out[o] = accl[ch*65 + tt] + x[o];   // RES_SCALE = 1.0
    }
}

// ---------------- launcher ----------------
extern "C" void kernel_launch(void* const* d_in, const int* in_sizes, int n_in,
                              void* d_out, int out_size, void* d_ws, size_t ws_size,
                              hipStream_t stream)
{
    const float* x    = (const float*)d_in[0];
    const float* rot  = (const float*)d_in[1];
    const float* wm   = (const float*)d_in[2];
    const float* bm   = (const float*)d_in[3];
    const float* wa   = (const float*)d_in[4];
    const float* ba   = (const float*)d_in[5];
    const float* wf   = (const float*)d_in[6];
    const float* bf   = (const float*)d_in[7];
    const float* fc1w = (const float*)d_in[8];
    const float* fc1b = (const float*)d_in[9];
    const float* fc2w = (const float*)d_in[10];
    const float* fc2b = (const float*)d_in[11];
    float* out = (float*)d_out;

    char* ws = (char*)d_ws;
    // pre-sort stage
    unsigned short* xeb  = (unsigned short*)(ws + 0);         // 2*9216*16 bf16
    unsigned short* yeb  = (unsigned short*)(ws + 589824);    // 2*9216*64 bf16
    unsigned short* xnb  = (unsigned short*)(ws + 2949120);   // 2*9216*16 bf16
    unsigned short* feb  = (unsigned short*)(ws + 3538944);   // 2*9216*64 bf16 (-> 5,898,240)
    unsigned short* wpak = (unsigned short*)(ws + 8911872);   // 128*576 bf16
    unsigned char* codes = (unsigned char*)(ws + 9059328);    // 2*36864 u8
    int* hist            = (int*)(ws + 9133056);              // 2*256*144 i32
    int* idxb            = (int*)(ws + 9427968);              // 2*36864 i32 (-> 9,722,880)
    // post-sort stage. rets/bscs ALIAS the pre-sort region (dead after k_gather).
    // w1bf/w2bf moved PAST the streams: k_attn reads them while writing rets.
    unsigned short* rets = (unsigned short*)(ws + 0);         // 8*9216*64 bf16 (9,437,184)
    float* bscs          = (float*)(ws + 9437184);            // 8*9216 f32
    unsigned short* qs   = (unsigned short*)(ws + 9732096);   // 8*9216*16 bf16
    unsigned short* ks   = (unsigned short*)(ws + 12091392);  // 8*9216*16 bf16
    unsigned short* vs   = (unsigned short*)(ws + 14450688);  // 8*9216*64 bf16
    unsigned short* fes  = (unsigned short*)(ws + 23887872);  // 8*9216*64 bf16
    int* undo            = (int*)(ws + 33325056);             // 8*9216 i32
    unsigned short* w1bf = (unsigned short*)(ws + 33619968);  // 144*64 bf16
    unsigned short* w2bf = (unsigned short*)(ws + 33638400);  // 144*160 bf16 (end 33,684,480)

    k_front    <<<576, 256, 0, stream>>>(x, wm, bm, rot, xeb, xnb, codes,
                                         fc1w, fc2w, wa, wf, w1bf, w2bf, wpak);
    k_convbf_fc<<<672, 256, 0, stream>>>(x, wpak, ba, bf, yeb, feb, codes, hist);
    k_scan     <<<2,    256, 0, stream>>>(hist);
    k_place    <<<288,  256, 0, stream>>>(codes, hist, idxb);
    k_gather   <<<1152, 256, 0, stream>>>(idxb, xeb, xnb, yeb, feb,
                                          qs, ks, vs, fes, undo);
    k_attn     <<<512,  256, 0, stream>>>(qs, ks, vs, fes,
                                          w1bf, fc1b, w2bf, fc2b, rets, bscs);
    k_final    <<<288,  256, 0, stream>>>(rets, bscs, undo, x, out);
}

// Round 4
// 256.900 us; speedup vs baseline: 1.5774x; 1.5774x over previous
//
#include <hip/hip_runtime.h>
#include <hip/hip_bf16.h>

#define LL 9216            // 96*96
#define TOT 36864          // 4*LL
#define CHK 144
#define NSEG 144
#define EPS_N 5e-5f

typedef __bf16 bf16x8 __attribute__((ext_vector_type(8)));
typedef float f32x4 __attribute__((ext_vector_type(4)));

__device__ __forceinline__ float dot4(float4 a, float4 b) {
    return a.x*b.x + a.y*b.y + a.z*b.z + a.w*b.w;
}
__device__ __forceinline__ unsigned short f2bf(float f) {
    __hip_bfloat16 h = __float2bfloat16(f);
    return *reinterpret_cast<unsigned short*>(&h);
}
__device__ __forceinline__ float bf2f(unsigned short u) {
    return __uint_as_float(((unsigned int)u) << 16);
}

// ---------------- K1: xe conv + LSH codes + bf16 xeb/xnb + weight prep -----------
// blocks 0..287: conv 8x8 tile + codes; blocks 288..575: weight prep. 46 KB LDS.
__global__ __launch_bounds__(256) void k_front(
    const float* __restrict__ x, const float* __restrict__ wm,
    const float* __restrict__ bm, const float* __restrict__ rot,
    unsigned short* __restrict__ xeb, unsigned short* __restrict__ xnb,
    unsigned char* __restrict__ codes,
    const float* __restrict__ fc1w, const float* __restrict__ fc2w,
    const float* __restrict__ wa, const float* __restrict__ wf,
    unsigned short* __restrict__ w1bf, unsigned short* __restrict__ w2bf,
    unsigned short* __restrict__ wpack)
{
    int tid = threadIdx.x;
    if (blockIdx.x >= 288) {   // ---- weight prep ----
        int i = (blockIdx.x - 288) * 256 + tid;
        if (i < 144 * 64) w1bf[i] = f2bf(fc1w[i]);
        if (i < 144 * 160) {
            int r = i / 160, c = i - r * 160;
            w2bf[i] = (c < 144) ? f2bf(fc2w[r * 144 + c]) : 0;
        }
        if (i < 128 * 576) {
            int o = i / 576, kk = i - o * 576;
            int dydx = kk >> 6, c = kk & 63;
            const float* src = (o < 64) ? wa : wf;
            wpack[i] = f2bf(src[(o & 63) * 576 + c * 9 + dydx]);
        }
        return;
    }
    __shared__ float xl[6400];       // [64][10][10] halo tile (25.6 KB)
    __shared__ float rotT[4096];     // [h*64+i][16]          (16 KB)
    __shared__ float xsp[64 * 20];   // [pos][ch pad20]       (5 KB)
    int b = blockIdx.x;
    int n = b / 144, tile = b % 144;
    int ty0 = (tile / 12) * 8, tx0 = (tile % 12) * 8;
    for (int li = tid; li < 6400; li += 256) {
        int c = li / 100, s = li % 100;
        int yy = s / 10, xx = s % 10;
        int gy = ty0 + yy - 1, gx = tx0 + xx - 1;
        float v = 0.f;
        if ((unsigned)gy < 96u && (unsigned)gx < 96u)
            v = x[((n * 64 + c) * 96 + gy) * 96 + gx];
        xl[li] = v;
    }
    for (int e = tid; e < 4096; e += 256) {
        int f = e >> 8, r = e & 255;
        rotT[r * 16 + f] = rot[f * 256 + r];   // rot is (16,4,64)
    }
    __syncthreads();
    int p = tid & 63, og = tid >> 6;
    int row = p >> 3, col = p & 7;
    int ogs = __builtin_amdgcn_readfirstlane(og);   // wave-uniform -> s_load path
    const float* wb = wm + (size_t)ogs * 4 * 576;
    float acc0 = 0.f, acc1 = 0.f, acc2 = 0.f, acc3 = 0.f;
    for (int c = 0; c < 64; ++c) {
        float xp[9];
        int base = c * 100 + row * 10 + col;
        #pragma unroll
        for (int dy = 0; dy < 3; ++dy)
            #pragma unroll
            for (int dx = 0; dx < 3; ++dx)
                xp[dy * 3 + dx] = xl[base + dy * 10 + dx];
        const float* w0 = wb + c * 9;
        #pragma unroll
        for (int u = 0; u < 9; ++u) {
            acc0 += w0[u]        * xp[u];
            acc1 += w0[576 + u]  * xp[u];
            acc2 += w0[1152 + u] * xp[u];
            acc3 += w0[1728 + u] * xp[u];
        }
    }
    int o = ogs * 4;
    float v0 = acc0 + bm[o + 0]; v0 = v0 > 0.f ? v0 : 0.f;
    float v1 = acc1 + bm[o + 1]; v1 = v1 > 0.f ? v1 : 0.f;
    float v2 = acc2 + bm[o + 2]; v2 = v2 > 0.f ? v2 : 0.f;
    float v3 = acc3 + bm[o + 3]; v3 = v3 > 0.f ? v3 : 0.f;
    size_t t = (size_t)n * LL + (ty0 + row) * 96 + tx0 + col;
    unsigned short pk[4] = {f2bf(v0), f2bf(v1), f2bf(v2), f2bf(v3)};
    *(uint2*)(xeb + t * 16 + o) = *(uint2*)pk;
    *(float4*)(xsp + p * 20 + o) = make_float4(v0, v1, v2, v3);
    __syncthreads();
    // ---- codes phase: thread = (pos = tid&63, h = tid>>6) ----
    int pos = tid & 63, h = tid >> 6;
    int prow = pos >> 3, pcol = pos & 7;
    size_t tc = (size_t)n * LL + (ty0 + prow) * 96 + tx0 + pcol;
    float4 q0 = *(float4*)(xsp + pos * 20 + 0);
    float4 q1 = *(float4*)(xsp + pos * 20 + 4);
    float4 q2 = *(float4*)(xsp + pos * 20 + 8);
    float4 q3 = *(float4*)(xsp + pos * 20 + 12);
    if (h == 0) {
        float nn = dot4(q0,q0) + dot4(q1,q1) + dot4(q2,q2) + dot4(q3,q3);
        float s = fmaxf(sqrtf(nn), EPS_N);
        float inv = 1.f / s;
        unsigned short pn[16];
        pn[0]=f2bf(q0.x*inv);  pn[1]=f2bf(q0.y*inv);  pn[2]=f2bf(q0.z*inv);  pn[3]=f2bf(q0.w*inv);
        pn[4]=f2bf(q1.x*inv);  pn[5]=f2bf(q1.y*inv);  pn[6]=f2bf(q1.z*inv);  pn[7]=f2bf(q1.w*inv);
        pn[8]=f2bf(q2.x*inv);  pn[9]=f2bf(q2.y*inv);  pn[10]=f2bf(q2.z*inv); pn[11]=f2bf(q2.w*inv);
        pn[12]=f2bf(q3.x*inv); pn[13]=f2bf(q3.y*inv); pn[14]=f2bf(q3.z*inv); pn[15]=f2bf(q3.w*inv);
        *(uint4*)(xnb + tc * 16)     = ((uint4*)pn)[0];
        *(uint4*)(xnb + tc * 16 + 8) = ((uint4*)pn)[1];
    }
    float best = -1e30f; int bi = 0;
    const float* rp = rotT + h * 1024;
    for (int i = 0; i < 64; ++i) {
        const float4* r4 = (const float4*)(rp + i * 16);
        float v = dot4(q0, r4[0]) + dot4(q1, r4[1]) + dot4(q2, r4[2]) + dot4(q3, r4[3]);
        if (v > best) { best = v; bi = i; }   // strict > = first max (jnp.argmax)
    }
    codes[(size_t)n * TOT + h * LL + (tc - (size_t)n * LL)] = (unsigned char)(h * 64 + bi);
}

// ---------------- K2: ye/fe conv bf16 MFMA + fused fc1/relu/fc2 + fused hist -----
__global__ __launch_bounds__(256) void k_convbf_fc(
    const float* __restrict__ x, const unsigned short* __restrict__ wpack,
    const float* __restrict__ ba, const float* __restrict__ bfb,
    const unsigned short* __restrict__ w1bf, const float* __restrict__ fc1_b,
    const unsigned short* __restrict__ w2bf, const float* __restrict__ fc2_b,
    unsigned short* __restrict__ yeb, unsigned short* __restrict__ re2b,
    const unsigned char* __restrict__ codes, int* __restrict__ hist)
{
    __shared__ unsigned short xt[3 * 50 * 72];   // input halo strip, ch-inner
    __shared__ unsigned short fet[48 * 72];      // fe tile [pos][ch]
    __shared__ unsigned short hb [48 * 168];     // hid [pos][m pad160]
    __shared__ int lh[256];
    int tid = threadIdx.x;
    if (blockIdx.x >= 384) {   // ---- histogram branch ----
        int b2 = blockIdx.x - 384;
        int n = b2 / NSEG, seg = b2 % NSEG;
        lh[tid] = 0;
        __syncthreads();
        int code = codes[(size_t)n * TOT + seg * 256 + tid];
        atomicAdd(&lh[code], 1);
        __syncthreads();
        hist[((size_t)n * 256 + tid) * NSEG + seg] = lh[tid];
        return;
    }
    int b = blockIdx.x;
    int n = b / 192, rem = b % 192;
    int y = rem >> 1, strip = rem & 1;
    int x0 = strip * 48;
    for (int e = tid; e < 9600; e += 256) {
        int r = e / 3200, r2 = e - r * 3200;
        int c = r2 / 50, j = r2 - c * 50;
        int gy = y - 1 + r, gx = x0 - 1 + j;
        float v = 0.f;
        if ((unsigned)gy < 96u && (unsigned)gx < 96u)
            v = x[((n * 64 + c) * 96 + gy) * 96 + gx];
        xt[(r * 50 + j) * 72 + c] = f2bf(v);
    }
    for (int e = tid; e < 384; e += 256) {       // hb K-pad zero (cols 144..159)
        int r = e >> 3, pq = e & 7;
        *(unsigned int*)(hb + r * 168 + 144 + pq * 2) = 0;
    }
    __syncthreads();
    int wave = tid >> 6, lane = tid & 63;
    int n16 = lane & 15, quad = lane >> 4;
    f32x4 acc[2][3];
    #pragma unroll
    for (int mi = 0; mi < 2; ++mi)
        #pragma unroll
        for (int nt = 0; nt < 3; ++nt) acc[mi][nt] = (f32x4){0.f, 0.f, 0.f, 0.f};
    #pragma unroll
    for (int s = 0; s < 18; ++s) {
        int dydx = s >> 1, half = s & 1;
        int dy = dydx / 3, dxm = dydx - dy * 3;
        bf16x8 B[3];
        #pragma unroll
        for (int nt = 0; nt < 3; ++nt) {
            int j = nt * 16 + n16 + dxm;
            B[nt] = *(bf16x8*)(xt + (dy * 50 + j) * 72 + half * 32 + quad * 8);
        }
        #pragma unroll
        for (int mi = 0; mi < 2; ++mi) {
            int o = (wave * 2 + mi) * 16 + n16;
            bf16x8 A = *(const bf16x8*)(wpack + o * 576 + dydx * 64 + half * 32 + quad * 8);
            #pragma unroll
            for (int nt = 0; nt < 3; ++nt)
                acc[mi][nt] = __builtin_amdgcn_mfma_f32_16x16x32_bf16(A, B[nt], acc[mi][nt], 0, 0, 0);
        }
    }
    #pragma unroll
    for (int mi = 0; mi < 2; ++mi) {
        int mt = wave * 2 + mi;
        int obase = mt * 16 + quad * 4;          // 0..124, multiple of 4
        float4 b4 = (mt < 4) ? *(const float4*)(ba + obase)
                             : *(const float4*)(bfb + obase - 64);
        #pragma unroll
        for (int nt = 0; nt < 3; ++nt) {
            int j = nt * 16 + n16;               // local position 0..47
            unsigned short pk[4];
            float v0 = acc[mi][nt][0] + b4.x; pk[0] = f2bf(v0 > 0.f ? v0 : 0.f);
            float v1 = acc[mi][nt][1] + b4.y; pk[1] = f2bf(v1 > 0.f ? v1 : 0.f);
            float v2 = acc[mi][nt][2] + b4.z; pk[2] = f2bf(v2 > 0.f ? v2 : 0.f);
            float v3 = acc[mi][nt][3] + b4.w; pk[3] = f2bf(v3 > 0.f ? v3 : 0.f);
            if (mt < 4) {
                size_t t = (size_t)n * LL + y * 96 + x0 + j;
                *(uint2*)(yeb + t * 64 + obase) = *(uint2*)pk;
            } else {
                *(uint2*)(fet + j * 72 + (obase - 64)) = *(uint2*)pk;
            }
        }
    }
    __syncthreads();
    size_t R0 = (size_t)n * LL + y * 96 + x0;
    // GEMM1: hid = relu(fe @ w1^T + b1)
    for (int nt = wave; nt < 9; nt += 4) {
        int bn = nt * 16 + n16;
        bf16x8 b0 = *(const bf16x8*)(w1bf + bn * 64 + quad * 8);
        bf16x8 b1 = *(const bf16x8*)(w1bf + bn * 64 + 32 + quad * 8);
        float bb = fc1_b[bn];
        #pragma unroll
        for (int m = 0; m < 3; ++m) {
            int arow = m * 16 + n16;
            bf16x8 a0 = *(bf16x8*)(fet + arow * 72 + quad * 8);
            bf16x8 a1 = *(bf16x8*)(fet + arow * 72 + 32 + quad * 8);
            f32x4 c2 = {0.f, 0.f, 0.f, 0.f};
            c2 = __builtin_amdgcn_mfma_f32_16x16x32_bf16(a0, b0, c2, 0, 0, 0);
            c2 = __builtin_amdgcn_mfma_f32_16x16x32_bf16(a1, b1, c2, 0, 0, 0);
            #pragma unroll
            for (int r = 0; r < 4; ++r) {
                float v = c2[r] + bb;
                hb[(m * 16 + quad * 4 + r) * 168 + bn] = f2bf(v > 0.f ? v : 0.f);
            }
        }
    }
    __syncthreads();
    // GEMM2: re2 = hid @ w2^T + b2 (K=160)
    for (int nt = wave; nt < 9; nt += 4) {
        int bn = nt * 16 + n16;
        bf16x8 wv2[5];
        #pragma unroll
        for (int kk = 0; kk < 5; ++kk)
            wv2[kk] = *(const bf16x8*)(w2bf + bn * 160 + kk * 32 + quad * 8);
        float bb = fc2_b[bn];
        #pragma unroll
        for (int m = 0; m < 3; ++m) {
            int arow = m * 16 + n16;
            f32x4 c2 = {0.f, 0.f, 0.f, 0.f};
            #pragma unroll
            for (int kk = 0; kk < 5; ++kk) {
                bf16x8 a = *(bf16x8*)(hb + arow * 168 + kk * 32 + quad * 8);
                c2 = __builtin_amdgcn_mfma_f32_16x16x32_bf16(a, wv2[kk], c2, 0, 0, 0);
            }
            #pragma unroll
            for (int r = 0; r < 4; ++r)
                re2b[(R0 + m * 16 + quad * 4 + r) * 144 + bn] = f2bf(c2[r] + bb);
        }
    }
}

// ---------------- K3: counting sort scan + place --------------------------------
__global__ void k_scan(int* __restrict__ hist)
{
    __shared__ int sc[256];
    int n = blockIdx.x, bin = threadIdx.x;
    int* hp = hist + ((size_t)n * 256 + bin) * NSEG;
    int4 buf[36];
    int4* hp4 = (int4*)hp;
    #pragma unroll
    for (int q = 0; q < 36; ++q) buf[q] = hp4[q];
    int running = 0;
    #pragma unroll
    for (int q = 0; q < 36; ++q) {
        int t0 = buf[q].x; buf[q].x = running; running += t0;
        int t1 = buf[q].y; buf[q].y = running; running += t1;
        int t2 = buf[q].z; buf[q].z = running; running += t2;
        int t3 = buf[q].w; buf[q].w = running; running += t3;
    }
    sc[bin] = running;
    __syncthreads();
    for (int off = 1; off < 256; off <<= 1) {
        int v = sc[bin];
        int u = (bin >= off) ? sc[bin - off] : 0;
        __syncthreads();
        sc[bin] = v + u;
        __syncthreads();
    }
    int bs = sc[bin] - running;   // exclusive prefix over bins
    #pragma unroll
    for (int q = 0; q < 36; ++q) {
        buf[q].x += bs; buf[q].y += bs; buf[q].z += bs; buf[q].w += bs;
        hp4[q] = buf[q];
    }
}

__global__ __launch_bounds__(256) void k_place(
    const unsigned char* __restrict__ codes, const int* __restrict__ hist,
    int* __restrict__ idx)
{
    __shared__ unsigned char cl[256];
    int b = blockIdx.x, n = b / NSEG, seg = b % NSEG;
    int tid = threadIdx.x;
    int my = codes[(size_t)n * TOT + seg * 256 + tid];
    cl[tid] = (unsigned char)my;
    __syncthreads();
    int rank = 0;
    for (int j = 0; j < tid; ++j) rank += (cl[j] == my);
    int pos = hist[((size_t)n * 256 + my) * NSEG + seg] + rank;
    idx[(size_t)n * TOT + pos] = seg * 256 + tid;
}

// ---------------- K3b: materialize sorted operand streams -----------------------
// Sorts q/k/v/fc-score rows into bucket order once (scattered reads, dense
// writes) so k_attn sees only contiguous affine spans. Also writes the inverse
// permutation (undo) for k_final.
__global__ __launch_bounds__(256) void k_gather(
    const int* __restrict__ idx, const unsigned short* __restrict__ xeb,
    const unsigned short* __restrict__ xnb, const unsigned short* __restrict__ yeb,
    const unsigned short* __restrict__ re2b,
    unsigned short* __restrict__ qs, unsigned short* __restrict__ ks,
    unsigned short* __restrict__ vs, unsigned short* __restrict__ fs,
    int* __restrict__ undo)
{
    __shared__ int tl[64];
    int b = blockIdx.x;
    int nh = b / 144, grp = b % 144;            // nh = n*4+h, 64 sorted slots per block
    int n = nh >> 2, h = nh & 3;
    size_t sbase = (size_t)nh * LL + grp * 64;
    size_t nL = (size_t)n * LL;
    int tid = threadIdx.x;
    if (tid < 64) {
        int t = idx[(size_t)n * TOT + h * LL + grp * 64 + tid] - h * LL;
        tl[tid] = t;
        undo[(size_t)nh * LL + t] = grp * 64 + tid;
    }
    __syncthreads();
    // qs/ks: 2x16B per slot
    for (int e = tid; e < 128; e += 256) {
        int s = e >> 1, c = e & 1;
        size_t src = (nL + tl[s]) * 16 + c * 8;
        *(uint4*)(qs + (sbase + s) * 16 + c * 8) = *(const uint4*)(xeb + src);
        *(uint4*)(ks + (sbase + s) * 16 + c * 8) = *(const uint4*)(xnb + src);
    }
    // vs: 8x16B per slot (8 lanes cooperate per row)
    for (int e = tid; e < 512; e += 256) {
        int s = e >> 3, c = e & 7;
        *(uint4*)(vs + (sbase + s) * 64 + c * 8) =
            *(const uint4*)(yeb + (nL + tl[s]) * 64 + c * 8);
    }
    // fs: 18x16B per slot (18 lanes per row)
    for (int e = tid; e < 64 * 18; e += 256) {
        int s = e / 18, c = e - s * 18;
        *(uint4*)(fs + (sbase + s) * 144 + c * 8) =
            *(const uint4*)(re2b + (nL + tl[s]) * 144 + c * 8);
    }
}

// ---------------- K4: bucketed attention — one query tile per wave --------------
// R14. Three structures (R0/R1/R2) all hit a ~75-85us latency equilibrium at
// 8 waves/CU (MfmaUtil ~4%, VALUBusy ~20%, HBM ~20% -- all pipes idle); R3's
// FC-recompute spilled (FETCH~WRITE~230MB). The binding constraint is residency
// + imbalance, so: 4608 wave-jobs (512 buckets x 9 query tiles), grid 1152x256,
// each WAVE owns one 16-row query tile end-to-end, zero barriers. Per-wave LDS:
// Vt slice 8KB (XOR-swizzled, R1-verified) + P 1.75KB -> 39.9KB/block ->
// 4 blocks/CU = 16 waves/CU (2x). ~90 VGPR -> launch_bounds(256,4) w/o spill.
// All loads are affine into the sorted streams; same-wave LDS write->read needs
// no barrier (in-order LDS per wave, R1 precedent). Block remap: each XCD gets
// one (n,h) group (~4.4MB stream set) for L2 reuse of the 9x tile re-reads.
__global__ __launch_bounds__(256, 4) void k_attn(
    const unsigned short* __restrict__ qs, const unsigned short* __restrict__ ks,
    const unsigned short* __restrict__ vs, const unsigned short* __restrict__ fs,
    unsigned short* __restrict__ rets, float* __restrict__ bscs)
{
    __shared__ __align__(16) unsigned short Vt[4][64 * 64]; // per-wave V^T swizzled (32 KB)
    __shared__ __align__(16) unsigned short Pw[4][16 * 56]; // per-wave P (7 KB)

    int B = blockIdx.x;
    int wb = (B & 7) * 144 + (B >> 3);          // XCD x -> contiguous 144 blocks = one (n,h)
    int tid = threadIdx.x;
    int lane = tid & 63, wv = tid >> 6;
    int n16 = lane & 15, quad = lane >> 4;
    int job = wb * 4 + wv;                      // 0..4607
    int bucket = job / 9, mt = job - bucket * 9;
    int n = bucket >> 8, rem = bucket & 255;
    int h = rem >> 6, k = rem & 63;

    size_t hL = (size_t)(n * 4 + h) * LL;
    size_t sp0 = hL + (size_t)k * 144;
    size_t sp1 = hL + (size_t)((k + 63) & 63) * 144;
    size_t sp2 = hL + (size_t)((k + 1) & 63) * 144;

    unsigned short* Vw = &Vt[wv][0];
    unsigned short* Pp = &Pw[wv][0];
    int su = lane & 7, jp = lane >> 3;          // V staging: channel chunk su, j-pair jp

    // zero swizzled pad slots j=48..63 once (PV kk=1 quads 2,3 read them;
    // A side is zero there but NaN-pattern garbage in B would poison the MFMA)
    #pragma unroll
    for (int e = 0; e < 8; ++e) {
        int i2 = e * 64 + lane;
        int c = i2 >> 3, j = 48 + (i2 & 7) * 2;
        int bp = ((j >> 3) ^ (c >> 3) ^ (((c >> 2) & 1) << 2)) & 7;
        *(unsigned int*)(Vw + c * 64 + bp * 8 + (j & 7)) = 0;
    }

    // query A-fragment: K=16 real, padded to 32 via zero quads>=2
    bf16x8 afragQ = {};
    if (quad < 2)
        afragQ = *(const bf16x8*)(qs + (sp0 + mt * 16 + n16) * 16 + quad * 8);

    f32x4 acc[4];                               // [ct]: channels ct*16+n16
    float rm[4], rl[4];
    #pragma unroll
    for (int ct = 0; ct < 4; ++ct) acc[ct] = (f32x4){0.f, 0.f, 0.f, 0.f};
    #pragma unroll
    for (int r = 0; r < 4; ++r) { rm[r] = -1e30f; rl[r] = 0.f; }

    #pragma unroll
    for (int reg = 0; reg < 3; ++reg) {
        size_t sb0 = (reg == 0) ? sp0 : ((reg == 1) ? sp1 : sp2);
        #pragma unroll
        for (int sub = 0; sub < 3; ++sub) {
            size_t sb = sb0 + sub * 48;
            // ---- issue all of this tile's loads (affine, independent) ----
            uint4 va[3], vb[3];
            #pragma unroll
            for (int il = 0; il < 3; ++il) {
                size_t r = sb + (il * 8 + jp) * 2;
                va[il] = *(const uint4*)(vs + r * 64 + su * 8);
                vb[il] = *(const uint4*)(vs + (r + 1) * 64 + su * 8);
            }
            bf16x8 ksf[3] = {};
            if (quad < 2) {
                ksf[0] = *(const bf16x8*)(ks + (sb + n16) * 16 + quad * 8);
                ksf[1] = *(const bf16x8*)(ks + (sb + 16 + n16) * 16 + quad * 8);
                ksf[2] = *(const bf16x8*)(ks + (sb + 32 + n16) * 16 + quad * 8);
            }
            ushort4 fv[3];
            #pragma unroll
            for (int nt = 0; nt < 3; ++nt)
                fv[nt] = *(const ushort4*)(fs + (sb + nt * 16 + n16) * 144
                                           + mt * 16 + quad * 4);
            // ---- spill V to own swizzled slice ----
            #pragma unroll
            for (int il = 0; il < 3; ++il) {
                int j0 = (il * 8 + jp) * 2;
                const unsigned short* pa = (const unsigned short*)&va[il];
                const unsigned short* pb = (const unsigned short*)&vb[il];
                int B0 = j0 >> 3, jlo = j0 & 7;
                #pragma unroll
                for (int ci = 0; ci < 8; ++ci) {
                    int c = su * 8 + ci;
                    int bp = (B0 ^ (c >> 3) ^ (((c >> 2) & 1) << 2)) & 7;
                    *(unsigned int*)(Vw + c * 64 + bp * 8 + jlo) =
                        (unsigned int)pa[ci] | ((unsigned int)pb[ci] << 16);
                }
            }
            // ---- QK via MFMA (C init = fc scores) ----
            f32x4 c0 = {bf2f(fv[0].x), bf2f(fv[0].y), bf2f(fv[0].z), bf2f(fv[0].w)};
            f32x4 c1 = {bf2f(fv[1].x), bf2f(fv[1].y), bf2f(fv[1].z), bf2f(fv[1].w)};
            f32x4 c2 = {bf2f(fv[2].x), bf2f(fv[2].y), bf2f(fv[2].z), bf2f(fv[2].w)};
            c0 = __builtin_amdgcn_mfma_f32_16x16x32_bf16(afragQ, ksf[0], c0, 0, 0, 0);
            c1 = __builtin_amdgcn_mfma_f32_16x16x32_bf16(afragQ, ksf[1], c1, 0, 0, 0);
            c2 = __builtin_amdgcn_mfma_f32_16x16x32_bf16(afragQ, ksf[2], c2, 0, 0, 0);
            // ---- online softmax (rows quad*4+r; reduce over n16) ----
            #pragma unroll
            for (int r = 0; r < 4; ++r) {
                float v0 = c0[r], v1 = c1[r], v2 = c2[r];
                float mm = fmaxf(fmaxf(v0, v1), v2);
                mm = fmaxf(mm, __shfl_xor(mm, 1, 16));
                mm = fmaxf(mm, __shfl_xor(mm, 2, 16));
                mm = fmaxf(mm, __shfl_xor(mm, 4, 16));
                mm = fmaxf(mm, __shfl_xor(mm, 8, 16));
                float mn = fmaxf(rm[r], mm);
                float a = __expf(rm[r] - mn);
                float s0 = __expf(v0 - mn), s1 = __expf(v1 - mn), s2 = __expf(v2 - mn);
                float ss = s0 + s1 + s2;
                ss += __shfl_xor(ss, 1, 16);
                ss += __shfl_xor(ss, 2, 16);
                ss += __shfl_xor(ss, 4, 16);
                ss += __shfl_xor(ss, 8, 16);
                rl[r] = rl[r] * a + ss;
                rm[r] = mn;
                acc[0][r] *= a; acc[1][r] *= a; acc[2][r] *= a; acc[3][r] *= a;
                int rw = quad * 4 + r;
                Pp[rw * 56 +      n16] = f2bf(s0);
                Pp[rw * 56 + 16 + n16] = f2bf(s1);
                Pp[rw * 56 + 32 + n16] = f2bf(s2);
            }
            // ---- PV via MFMA (same-wave LDS, no barrier needed) ----
            #pragma unroll
            for (int kk = 0; kk < 2; ++kk) {
                bf16x8 Bv[4];
                #pragma unroll
                for (int ct = 0; ct < 4; ++ct) {
                    int c = ct * 16 + n16;
                    int bp = ((kk * 4 + quad) ^ (c >> 3) ^ (((c >> 2) & 1) << 2)) & 7;
                    Bv[ct] = *(const bf16x8*)(Vw + c * 64 + bp * 8);
                }
                bf16x8 Ap = {};
                if (kk == 0)
                    Ap = *(const bf16x8*)(Pp + n16 * 56 + quad * 8);
                else if (quad < 2)
                    Ap = *(const bf16x8*)(Pp + n16 * 56 + 32 + quad * 8);
                #pragma unroll
                for (int ct = 0; ct < 4; ++ct)
                    acc[ct] = __builtin_amdgcn_mfma_f32_16x16x32_bf16(Ap, Bv[ct], acc[ct], 0, 0, 0);
            }
        }
    }

    // ---- epilogue: dense writes in sorted order ----
    if (n16 == 0) {
        #pragma unroll
        for (int r = 0; r < 4; ++r)
            bscs[sp0 + mt * 16 + quad * 4 + r] = rm[r] + __logf(rl[r]);
    }
    #pragma unroll
    for (int r = 0; r < 4; ++r) {
        float inv = 1.f / rl[r];
        #pragma unroll
        for (int ct = 0; ct < 4; ++ct)
            rets[(sp0 + mt * 16 + quad * 4 + r) * 64 + ct * 16 + n16] =
                f2bf(acc[ct][r] * inv);
    }
}

// ---------------- K5: softmax over rounds + residual, NCHW output ----------------
// Reads sorted rets/bscs through the undo permutation (scattered 128B-row reads).
__global__ __launch_bounds__(256) void k_final(
    const unsigned short* __restrict__ rets, const float* __restrict__ bscs,
    const int* __restrict__ undo, const float* __restrict__ x,
    float* __restrict__ out)
{
    __shared__ float pr[4][64];
    __shared__ int us[4][64];
    __shared__ float accl[64 * 65];
    int b = blockIdx.x, n = b / 144;
    int t0 = (b % 144) * 64;
    int tid = threadIdx.x;
    {
        int h = tid >> 6, tt = tid & 63;
        us[h][tt] = undo[((size_t)n * 4 + h) * LL + t0 + tt];
    }
    __syncthreads();
    if (tid < 64) {
        float b0 = bscs[((size_t)n * 4 + 0) * LL + us[0][tid]];
        float b1 = bscs[((size_t)n * 4 + 1) * LL + us[1][tid]];
        float b2 = bscs[((size_t)n * 4 + 2) * LL + us[2][tid]];
        float b3 = bscs[((size_t)n * 4 + 3) * LL + us[3][tid]];
        float mx = fmaxf(fmaxf(b0, b1), fmaxf(b2, b3));
        float e0 = __expf(b0-mx), e1 = __expf(b1-mx), e2 = __expf(b2-mx), e3 = __expf(b3-mx);
        float inv = 1.f / (e0 + e1 + e2 + e3);
        pr[0][tid] = e0*inv; pr[1][tid] = e1*inv; pr[2][tid] = e2*inv; pr[3][tid] = e3*inv;
    }
    __syncthreads();
    int cc = tid & 63, tt4 = tid >> 6;
    #pragma unroll
    for (int q = 0; q < 16; ++q) {
        int tt = tt4 + 4*q;
        float v = 0.f;
        #pragma unroll
        for (int h2 = 0; h2 < 4; ++h2)
            v += bf2f(rets[(((size_t)n*4 + h2)*LL + us[h2][tt])*64 + cc]) * pr[h2][tt];
        accl[cc*65 + tt] = v;
    }
    __syncthreads();
    int tt = tid & 63, c4 = tid >> 6;
    #pragma unroll
    for (int q = 0; q < 16; ++q) {
        int ch = c4 + 4*q;
        size_t o = ((size_t)n*64 + ch)*LL + t0 + tt;
        out[o] = accl[ch*65 + tt] + x[o];   // RES_SCALE = 1.0
    }
}

// ---------------- launcher ----------------
extern "C" void kernel_launch(void* const* d_in, const int* in_sizes, int n_in,
                              void* d_out, int out_size, void* d_ws, size_t ws_size,
                              hipStream_t stream)
{
    const float* x    = (const float*)d_in[0];
    const float* rot  = (const float*)d_in[1];
    const float* wm   = (const float*)d_in[2];
    const float* bm   = (const float*)d_in[3];
    const float* wa   = (const float*)d_in[4];
    const float* ba   = (const float*)d_in[5];
    const float* wf   = (const float*)d_in[6];
    const float* bf   = (const float*)d_in[7];
    const float* fc1w = (const float*)d_in[8];
    const float* fc1b = (const float*)d_in[9];
    const float* fc2w = (const float*)d_in[10];
    const float* fc2b = (const float*)d_in[11];
    float* out = (float*)d_out;

    char* ws = (char*)d_ws;
    // pre-sort stage
    unsigned short* xeb  = (unsigned short*)(ws + 0);         // 2*9216*16 bf16
    unsigned short* yeb  = (unsigned short*)(ws + 589824);    // 2*9216*64 bf16
    unsigned short* xnb  = (unsigned short*)(ws + 2949120);   // 2*9216*16 bf16
    unsigned short* re2b = (unsigned short*)(ws + 3538944);   // 2*9216*144 bf16
    unsigned short* w1bf = (unsigned short*)(ws + 8847360);   // 144*64 bf16
    unsigned short* w2bf = (unsigned short*)(ws + 8865792);   // 144*160 bf16
    unsigned short* wpak = (unsigned short*)(ws + 8911872);   // 128*576 bf16
    unsigned char* codes = (unsigned char*)(ws + 9059328);    // 2*36864 u8
    int* hist            = (int*)(ws + 9133056);              // 2*256*144 i32
    int* idxb            = (int*)(ws + 9427968);              // 2*36864 i32 -> 9,575,424
    // post-sort stage. rets/bscs ALIAS the pre-sort region (xeb..idxb), which is
    // dead once k_gather has run (k_attn reads only qs/ks/vs/fs).
    unsigned short* rets = (unsigned short*)(ws + 0);         // 8*9216*64 bf16 (9,437,184)
    float* bscs          = (float*)(ws + 9437184);            // 8*9216 f32
    unsigned short* qs   = (unsigned short*)(ws + 9732096);   // 8*9216*16 bf16
    unsigned short* ks   = (unsigned short*)(ws + 12091392);  // 8*9216*16 bf16
    unsigned short* vs   = (unsigned short*)(ws + 14450688);  // 8*9216*64 bf16
    unsigned short* fs   = (unsigned short*)(ws + 23887872);  // 8*9216*144 bf16
    int* undo            = (int*)(ws + 45121536);             // 8*9216 i32 (end 45,416,448)

    k_front    <<<576, 256, 0, stream>>>(x, wm, bm, rot, xeb, xnb, codes,
                                         fc1w, fc2w, wa, wf, w1bf, w2bf, wpak);
    k_convbf_fc<<<672, 256, 0, stream>>>(x, wpak, ba, bf, w1bf, fc1b, w2bf, fc2b,
                                         yeb, re2b, codes, hist);
    k_scan     <<<2,    256, 0, stream>>>(hist);
    k_place    <<<288,  256, 0, stream>>>(codes, hist, idxb);
    k_gather   <<<1152, 256, 0, stream>>>(idxb, xeb, xnb, yeb, re2b,
                                          qs, ks, vs, fs, undo);
    k_attn     <<<1152, 256, 0, stream>>>(qs, ks, vs, fs, rets, bscs);
    k_final    <<<288,  256, 0, stream>>>(rets, bscs, undo, x, out);
}

// Round 6
// 236.285 us; speedup vs baseline: 1.7150x; 1.0872x over previous
//
#include <hip/hip_runtime.h>
#include <hip/hip_bf16.h>

#define LL 9216            // 96*96
#define TOT 36864          // 4*LL
#define CHK 144
#define NSEG 144
#define EPS_N 5e-5f

typedef __bf16 bf16x8 __attribute__((ext_vector_type(8)));
typedef float f32x4 __attribute__((ext_vector_type(4)));

__device__ __forceinline__ float dot4(float4 a, float4 b) {
    return a.x*b.x + a.y*b.y + a.z*b.z + a.w*b.w;
}
__device__ __forceinline__ unsigned short f2bf(float f) {
    __hip_bfloat16 h = __float2bfloat16(f);
    return *reinterpret_cast<unsigned short*>(&h);
}
__device__ __forceinline__ float bf2f(unsigned short u) {
    return __uint_as_float(((unsigned int)u) << 16);
}

// ---------------- K1: xe conv + LSH codes + bf16 xeb/xnb + weight prep -----------
// blocks 0..287: conv 8x8 tile + codes; blocks 288..575: weight prep. 46 KB LDS.
__global__ __launch_bounds__(256) void k_front(
    const float* __restrict__ x, const float* __restrict__ wm,
    const float* __restrict__ bm, const float* __restrict__ rot,
    unsigned short* __restrict__ xeb, unsigned short* __restrict__ xnb,
    unsigned char* __restrict__ codes,
    const float* __restrict__ fc1w, const float* __restrict__ fc2w,
    const float* __restrict__ wa, const float* __restrict__ wf,
    unsigned short* __restrict__ w1bf, unsigned short* __restrict__ w2bf,
    unsigned short* __restrict__ wpack)
{
    int tid = threadIdx.x;
    if (blockIdx.x >= 288) {   // ---- weight prep ----
        int i = (blockIdx.x - 288) * 256 + tid;
        if (i < 144 * 64) w1bf[i] = f2bf(fc1w[i]);
        if (i < 144 * 160) {
            int r = i / 160, c = i - r * 160;
            w2bf[i] = (c < 144) ? f2bf(fc2w[r * 144 + c]) : 0;
        }
        if (i < 128 * 576) {
            int o = i / 576, kk = i - o * 576;
            int dydx = kk >> 6, c = kk & 63;
            const float* src = (o < 64) ? wa : wf;
            wpack[i] = f2bf(src[(o & 63) * 576 + c * 9 + dydx]);
        }
        return;
    }
    __shared__ float xl[6400];       // [64][10][10] halo tile (25.6 KB)
    __shared__ float rotT[4096];     // [h*64+i][16]          (16 KB)
    __shared__ float xsp[64 * 20];   // [pos][ch pad20]       (5 KB)
    int b = blockIdx.x;
    int n = b / 144, tile = b % 144;
    int ty0 = (tile / 12) * 8, tx0 = (tile % 12) * 8;
    for (int li = tid; li < 6400; li += 256) {
        int c = li / 100, s = li % 100;
        int yy = s / 10, xx = s % 10;
        int gy = ty0 + yy - 1, gx = tx0 + xx - 1;
        float v = 0.f;
        if ((unsigned)gy < 96u && (unsigned)gx < 96u)
            v = x[((n * 64 + c) * 96 + gy) * 96 + gx];
        xl[li] = v;
    }
    for (int e = tid; e < 4096; e += 256) {
        int f = e >> 8, r = e & 255;
        rotT[r * 16 + f] = rot[f * 256 + r];   // rot is (16,4,64)
    }
    __syncthreads();
    int p = tid & 63, og = tid >> 6;
    int row = p >> 3, col = p & 7;
    int ogs = __builtin_amdgcn_readfirstlane(og);   // wave-uniform -> s_load path
    const float* wb = wm + (size_t)ogs * 4 * 576;
    float acc0 = 0.f, acc1 = 0.f, acc2 = 0.f, acc3 = 0.f;
    for (int c = 0; c < 64; ++c) {
        float xp[9];
        int base = c * 100 + row * 10 + col;
        #pragma unroll
        for (int dy = 0; dy < 3; ++dy)
            #pragma unroll
            for (int dx = 0; dx < 3; ++dx)
                xp[dy * 3 + dx] = xl[base + dy * 10 + dx];
        const float* w0 = wb + c * 9;
        #pragma unroll
        for (int u = 0; u < 9; ++u) {
            acc0 += w0[u]        * xp[u];
            acc1 += w0[576 + u]  * xp[u];
            acc2 += w0[1152 + u] * xp[u];
            acc3 += w0[1728 + u] * xp[u];
        }
    }
    int o = ogs * 4;
    float v0 = acc0 + bm[o + 0]; v0 = v0 > 0.f ? v0 : 0.f;
    float v1 = acc1 + bm[o + 1]; v1 = v1 > 0.f ? v1 : 0.f;
    float v2 = acc2 + bm[o + 2]; v2 = v2 > 0.f ? v2 : 0.f;
    float v3 = acc3 + bm[o + 3]; v3 = v3 > 0.f ? v3 : 0.f;
    size_t t = (size_t)n * LL + (ty0 + row) * 96 + tx0 + col;
    unsigned short pk[4] = {f2bf(v0), f2bf(v1), f2bf(v2), f2bf(v3)};
    *(uint2*)(xeb + t * 16 + o) = *(uint2*)pk;
    *(float4*)(xsp + p * 20 + o) = make_float4(v0, v1, v2, v3);
    __syncthreads();
    // ---- codes phase: thread = (pos = tid&63, h = tid>>6) ----
    int pos = tid & 63, h = tid >> 6;
    int prow = pos >> 3, pcol = pos & 7;
    size_t tc = (size_t)n * LL + (ty0 + prow) * 96 + tx0 + pcol;
    float4 q0 = *(float4*)(xsp + pos * 20 + 0);
    float4 q1 = *(float4*)(xsp + pos * 20 + 4);
    float4 q2 = *(float4*)(xsp + pos * 20 + 8);
    float4 q3 = *(float4*)(xsp + pos * 20 + 12);
    if (h == 0) {
        float nn = dot4(q0,q0) + dot4(q1,q1) + dot4(q2,q2) + dot4(q3,q3);
        float s = fmaxf(sqrtf(nn), EPS_N);
        float inv = 1.f / s;
        unsigned short pn[16];
        pn[0]=f2bf(q0.x*inv);  pn[1]=f2bf(q0.y*inv);  pn[2]=f2bf(q0.z*inv);  pn[3]=f2bf(q0.w*inv);
        pn[4]=f2bf(q1.x*inv);  pn[5]=f2bf(q1.y*inv);  pn[6]=f2bf(q1.z*inv);  pn[7]=f2bf(q1.w*inv);
        pn[8]=f2bf(q2.x*inv);  pn[9]=f2bf(q2.y*inv);  pn[10]=f2bf(q2.z*inv); pn[11]=f2bf(q2.w*inv);
        pn[12]=f2bf(q3.x*inv); pn[13]=f2bf(q3.y*inv); pn[14]=f2bf(q3.z*inv); pn[15]=f2bf(q3.w*inv);
        *(uint4*)(xnb + tc * 16)     = ((uint4*)pn)[0];
        *(uint4*)(xnb + tc * 16 + 8) = ((uint4*)pn)[1];
    }
    float best = -1e30f; int bi = 0;
    const float* rp = rotT + h * 1024;
    for (int i = 0; i < 64; ++i) {
        const float4* r4 = (const float4*)(rp + i * 16);
        float v = dot4(q0, r4[0]) + dot4(q1, r4[1]) + dot4(q2, r4[2]) + dot4(q3, r4[3]);
        if (v > best) { best = v; bi = i; }   // strict > = first max (jnp.argmax)
    }
    codes[(size_t)n * TOT + h * LL + (tc - (size_t)n * LL)] = (unsigned char)(h * 64 + bi);
}

// ---------------- K2: ye/fe conv bf16 MFMA + fused fc1/relu/fc2 + fused hist -----
__global__ __launch_bounds__(256) void k_convbf_fc(
    const float* __restrict__ x, const unsigned short* __restrict__ wpack,
    const float* __restrict__ ba, const float* __restrict__ bfb,
    const unsigned short* __restrict__ w1bf, const float* __restrict__ fc1_b,
    const unsigned short* __restrict__ w2bf, const float* __restrict__ fc2_b,
    unsigned short* __restrict__ yeb, unsigned short* __restrict__ re2b,
    const unsigned char* __restrict__ codes, int* __restrict__ hist)
{
    __shared__ unsigned short xt[3 * 50 * 72];   // input halo strip, ch-inner
    __shared__ unsigned short fet[48 * 72];      // fe tile [pos][ch]
    __shared__ unsigned short hb [48 * 168];     // hid [pos][m pad160]
    __shared__ int lh[256];
    int tid = threadIdx.x;
    if (blockIdx.x >= 384) {   // ---- histogram branch ----
        int b2 = blockIdx.x - 384;
        int n = b2 / NSEG, seg = b2 % NSEG;
        lh[tid] = 0;
        __syncthreads();
        int code = codes[(size_t)n * TOT + seg * 256 + tid];
        atomicAdd(&lh[code], 1);
        __syncthreads();
        hist[((size_t)n * 256 + tid) * NSEG + seg] = lh[tid];
        return;
    }
    int b = blockIdx.x;
    int n = b / 192, rem = b % 192;
    int y = rem >> 1, strip = rem & 1;
    int x0 = strip * 48;
    for (int e = tid; e < 9600; e += 256) {
        int r = e / 3200, r2 = e - r * 3200;
        int c = r2 / 50, j = r2 - c * 50;
        int gy = y - 1 + r, gx = x0 - 1 + j;
        float v = 0.f;
        if ((unsigned)gy < 96u && (unsigned)gx < 96u)
            v = x[((n * 64 + c) * 96 + gy) * 96 + gx];
        xt[(r * 50 + j) * 72 + c] = f2bf(v);
    }
    for (int e = tid; e < 384; e += 256) {       // hb K-pad zero (cols 144..159)
        int r = e >> 3, pq = e & 7;
        *(unsigned int*)(hb + r * 168 + 144 + pq * 2) = 0;
    }
    __syncthreads();
    int wave = tid >> 6, lane = tid & 63;
    int n16 = lane & 15, quad = lane >> 4;
    f32x4 acc[2][3];
    #pragma unroll
    for (int mi = 0; mi < 2; ++mi)
        #pragma unroll
        for (int nt = 0; nt < 3; ++nt) acc[mi][nt] = (f32x4){0.f, 0.f, 0.f, 0.f};
    #pragma unroll
    for (int s = 0; s < 18; ++s) {
        int dydx = s >> 1, half = s & 1;
        int dy = dydx / 3, dxm = dydx - dy * 3;
        bf16x8 B[3];
        #pragma unroll
        for (int nt = 0; nt < 3; ++nt) {
            int j = nt * 16 + n16 + dxm;
            B[nt] = *(bf16x8*)(xt + (dy * 50 + j) * 72 + half * 32 + quad * 8);
        }
        #pragma unroll
        for (int mi = 0; mi < 2; ++mi) {
            int o = (wave * 2 + mi) * 16 + n16;
            bf16x8 A = *(const bf16x8*)(wpack + o * 576 + dydx * 64 + half * 32 + quad * 8);
            #pragma unroll
            for (int nt = 0; nt < 3; ++nt)
                acc[mi][nt] = __builtin_amdgcn_mfma_f32_16x16x32_bf16(A, B[nt], acc[mi][nt], 0, 0, 0);
        }
    }
    #pragma unroll
    for (int mi = 0; mi < 2; ++mi) {
        int mt = wave * 2 + mi;
        int obase = mt * 16 + quad * 4;          // 0..124, multiple of 4
        float4 b4 = (mt < 4) ? *(const float4*)(ba + obase)
                             : *(const float4*)(bfb + obase - 64);
        #pragma unroll
        for (int nt = 0; nt < 3; ++nt) {
            int j = nt * 16 + n16;               // local position 0..47
            unsigned short pk[4];
            float v0 = acc[mi][nt][0] + b4.x; pk[0] = f2bf(v0 > 0.f ? v0 : 0.f);
            float v1 = acc[mi][nt][1] + b4.y; pk[1] = f2bf(v1 > 0.f ? v1 : 0.f);
            float v2 = acc[mi][nt][2] + b4.z; pk[2] = f2bf(v2 > 0.f ? v2 : 0.f);
            float v3 = acc[mi][nt][3] + b4.w; pk[3] = f2bf(v3 > 0.f ? v3 : 0.f);
            if (mt < 4) {
                size_t t = (size_t)n * LL + y * 96 + x0 + j;
                *(uint2*)(yeb + t * 64 + obase) = *(uint2*)pk;
            } else {
                *(uint2*)(fet + j * 72 + (obase - 64)) = *(uint2*)pk;
            }
        }
    }
    __syncthreads();
    size_t R0 = (size_t)n * LL + y * 96 + x0;
    // GEMM1: hid = relu(fe @ w1^T + b1)
    for (int nt = wave; nt < 9; nt += 4) {
        int bn = nt * 16 + n16;
        bf16x8 b0 = *(const bf16x8*)(w1bf + bn * 64 + quad * 8);
        bf16x8 b1 = *(const bf16x8*)(w1bf + bn * 64 + 32 + quad * 8);
        float bb = fc1_b[bn];
        #pragma unroll
        for (int m = 0; m < 3; ++m) {
            int arow = m * 16 + n16;
            bf16x8 a0 = *(bf16x8*)(fet + arow * 72 + quad * 8);
            bf16x8 a1 = *(bf16x8*)(fet + arow * 72 + 32 + quad * 8);
            f32x4 c2 = {0.f, 0.f, 0.f, 0.f};
            c2 = __builtin_amdgcn_mfma_f32_16x16x32_bf16(a0, b0, c2, 0, 0, 0);
            c2 = __builtin_amdgcn_mfma_f32_16x16x32_bf16(a1, b1, c2, 0, 0, 0);
            #pragma unroll
            for (int r = 0; r < 4; ++r) {
                float v = c2[r] + bb;
                hb[(m * 16 + quad * 4 + r) * 168 + bn] = f2bf(v > 0.f ? v : 0.f);
            }
        }
    }
    __syncthreads();
    // GEMM2: re2 = hid @ w2^T + b2 (K=160)
    for (int nt = wave; nt < 9; nt += 4) {
        int bn = nt * 16 + n16;
        bf16x8 wv2[5];
        #pragma unroll
        for (int kk = 0; kk < 5; ++kk)
            wv2[kk] = *(const bf16x8*)(w2bf + bn * 160 + kk * 32 + quad * 8);
        float bb = fc2_b[bn];
        #pragma unroll
        for (int m = 0; m < 3; ++m) {
            int arow = m * 16 + n16;
            f32x4 c2 = {0.f, 0.f, 0.f, 0.f};
            #pragma unroll
            for (int kk = 0; kk < 5; ++kk) {
                bf16x8 a = *(bf16x8*)(hb + arow * 168 + kk * 32 + quad * 8);
                c2 = __builtin_amdgcn_mfma_f32_16x16x32_bf16(a, wv2[kk], c2, 0, 0, 0);
            }
            #pragma unroll
            for (int r = 0; r < 4; ++r)
                re2b[(R0 + m * 16 + quad * 4 + r) * 144 + bn] = f2bf(c2[r] + bb);
        }
    }
}

// ---------------- K3: counting sort scan + place --------------------------------
__global__ void k_scan(int* __restrict__ hist)
{
    __shared__ int sc[256];
    int n = blockIdx.x, bin = threadIdx.x;
    int* hp = hist + ((size_t)n * 256 + bin) * NSEG;
    int4 buf[36];
    int4* hp4 = (int4*)hp;
    #pragma unroll
    for (int q = 0; q < 36; ++q) buf[q] = hp4[q];
    int running = 0;
    #pragma unroll
    for (int q = 0; q < 36; ++q) {
        int t0 = buf[q].x; buf[q].x = running; running += t0;
        int t1 = buf[q].y; buf[q].y = running; running += t1;
        int t2 = buf[q].z; buf[q].z = running; running += t2;
        int t3 = buf[q].w; buf[q].w = running; running += t3;
    }
    sc[bin] = running;
    __syncthreads();
    for (int off = 1; off < 256; off <<= 1) {
        int v = sc[bin];
        int u = (bin >= off) ? sc[bin - off] : 0;
        __syncthreads();
        sc[bin] = v + u;
        __syncthreads();
    }
    int bs = sc[bin] - running;   // exclusive prefix over bins
    #pragma unroll
    for (int q = 0; q < 36; ++q) {
        buf[q].x += bs; buf[q].y += bs; buf[q].z += bs; buf[q].w += bs;
        hp4[q] = buf[q];
    }
}

__global__ __launch_bounds__(256) void k_place(
    const unsigned char* __restrict__ codes, const int* __restrict__ hist,
    int* __restrict__ idx)
{
    __shared__ unsigned char cl[256];
    int b = blockIdx.x, n = b / NSEG, seg = b % NSEG;
    int tid = threadIdx.x;
    int my = codes[(size_t)n * TOT + seg * 256 + tid];
    cl[tid] = (unsigned char)my;
    __syncthreads();
    int rank = 0;
    for (int j = 0; j < tid; ++j) rank += (cl[j] == my);
    int pos = hist[((size_t)n * 256 + my) * NSEG + seg] + rank;
    idx[(size_t)n * TOT + pos] = seg * 256 + tid;
}

// ---------------- K3b: materialize sorted operand streams -----------------------
// R15: one block per (nh, chunk). Emits qs/ks (sorted rows), vsT (V TRANSPOSED
// [c][slot] per chunk, pair-packed u32 writes -> k_attn PV reads straight from
// global, no LDS staging), and fst (fc scores per-mt slices [slot][16] -> each
// attn wave streams a dense contiguous slice; every fetched line fully used).
// XCD swizzle matches k_attn so written lines are warm in the right L2.
__global__ __launch_bounds__(256) void k_gather(
    const int* __restrict__ idx, const unsigned short* __restrict__ xeb,
    const unsigned short* __restrict__ xnb, const unsigned short* __restrict__ yeb,
    const unsigned short* __restrict__ re2b,
    unsigned short* __restrict__ qs, unsigned short* __restrict__ ks,
    unsigned short* __restrict__ vsT, unsigned short* __restrict__ fst,
    int* __restrict__ undo)
{
    __shared__ int tl[144];
    int b0 = blockIdx.x;
    int b = ((b0 & 7) << 6) | (b0 >> 3);        // 512 = 8 x 64, bijective
    int nh = b >> 6, chunk = b & 63;
    int n = nh >> 2, h = nh & 3;
    size_t gb = (size_t)nh * LL + chunk * 144;  // sorted-global slot base
    size_t nL = (size_t)n * LL;
    int tid = threadIdx.x;
    if (tid < 144) {
        int t = idx[(size_t)n * TOT + h * LL + chunk * 144 + tid] - h * LL;
        tl[tid] = t;
        undo[(size_t)nh * LL + t] = chunk * 144 + tid;
    }
    __syncthreads();
    // qs/ks: 2x16B per slot
    for (int e = tid; e < 288; e += 256) {
        int s = e >> 1, half = e & 1;
        size_t src = (nL + tl[s]) * 16 + half * 8;
        *(uint4*)(qs + (gb + s) * 16 + half * 8) = *(const uint4*)(xeb + src);
        *(uint4*)(ks + (gb + s) * 16 + half * 8) = *(const uint4*)(xnb + src);
    }
    // vsT: [c][slot] transposed, slot-pairs packed as u32 (aligned, coalesced)
    size_t vb = (size_t)(nh * 64 + chunk) * 64;
    for (int e = tid; e < 576; e += 256) {
        int p = e % 72, su = e / 72;             // p = slot pair, su = 8-ch chunk
        uint4 a  = *(const uint4*)(yeb + (nL + tl[2 * p])     * 64 + su * 8);
        uint4 bq = *(const uint4*)(yeb + (nL + tl[2 * p + 1]) * 64 + su * 8);
        const unsigned short* pa = (const unsigned short*)&a;
        const unsigned short* pb = (const unsigned short*)&bq;
        #pragma unroll
        for (int ci = 0; ci < 8; ++ci) {
            int c = su * 8 + ci;
            *(unsigned int*)(vsT + (vb + c) * 144 + 2 * p) =
                (unsigned int)pa[ci] | ((unsigned int)pb[ci] << 16);
        }
    }
    // fst: per-mt slices, 32B contiguous per slot
    for (int e = tid; e < 1296; e += 256) {
        int mt = e / 144, s = e - mt * 144;
        const unsigned short* src = re2b + (nL + tl[s]) * 144 + mt * 16;
        unsigned short* dst = fst + ((size_t)(nh * 9 + mt) * LL + chunk * 144 + s) * 16;
        *(uint4*)(dst)     = *(const uint4*)(src);
        *(uint4*)(dst + 8) = *(const uint4*)(src + 8);
    }
}

// ---------------- K4: bucketed attention — 9 balanced waves, global V^T ---------
// R15/R16. R4 (wave-jobs, 4/block) hit L2 thrash: FETCH 92MB of a 384MB request
// stream, WRITE inflated 10x by dirty-line evictions; V requested 27x per chunk
// via per-wave LDS staging, fs used 8B per 64B line. Now: block = bucket,
// 576 threads = 9 waves, wave mt owns query tile mt (balanced; R1's 3/2/2/2
// critical path gone). PV B-frags read vsT DIRECTLY from global: the 6KB
// subtile is L1-shared by all 9 waves (9x on-CU reuse, 3x window reuse in L2),
// no LDS V staging, no barriers at all. fst slices stream dense per wave.
// LDS = per-wave P only (16 KB) -> 2 blocks/CU = 18 waves/CU.
// R16 hardening vs R15: launch_bounds (576,4) not (576,5); kk=1 quad>=2 B-load
// clamped in-row (its P operand is zero; avoids reading past the vsT row).
__global__ __launch_bounds__(576, 4) void k_attn(
    const unsigned short* __restrict__ qs, const unsigned short* __restrict__ ks,
    const unsigned short* __restrict__ vsT, const unsigned short* __restrict__ fst,
    unsigned short* __restrict__ rets, float* __restrict__ bscs)
{
    __shared__ __align__(16) unsigned short Pw[9][16 * 56];   // per-wave P (15.75 KB)

    int B = blockIdx.x;
    int bucket = ((B & 7) << 6) | (B >> 3);      // XCD x <-> (n,h) group x
    int n = bucket >> 8, rem = bucket & 255;
    int h = rem >> 6, k = rem & 63;
    int nh = n * 4 + h;
    int tid = threadIdx.x;
    int lane = tid & 63, mt = tid >> 6;          // wave = query tile 0..8
    int n16 = lane & 15, quad = lane >> 4;

    size_t hL = (size_t)nh * LL;
    int ch0 = k, ch1 = (k + 63) & 63, ch2 = (k + 1) & 63;
    unsigned short* Pp = &Pw[mt][0];
    const unsigned short* fsl = fst + (size_t)(nh * 9 + mt) * LL * 16;

    // query A-fragment: K=16 real, padded to 32 via zero quads>=2
    bf16x8 afragQ = {};
    if (quad < 2)
        afragQ = *(const bf16x8*)(qs + (hL + ch0 * 144 + mt * 16 + n16) * 16 + quad * 8);

    f32x4 acc[4];                                // [ct]: channels ct*16+n16
    float rm[4], rl[4];
    #pragma unroll
    for (int ct = 0; ct < 4; ++ct) acc[ct] = (f32x4){0.f, 0.f, 0.f, 0.f};
    #pragma unroll
    for (int r = 0; r < 4; ++r) { rm[r] = -1e30f; rl[r] = 0.f; }

    #pragma unroll
    for (int reg = 0; reg < 3; ++reg) {
        int chx = (reg == 0) ? ch0 : ((reg == 1) ? ch1 : ch2);
        int cb = chx * 144;                       // local slot base of the chunk
        const unsigned short* vchunk = vsT + (size_t)(nh * 64 + chx) * 64 * 144;
        #pragma unroll
        for (int sub = 0; sub < 3; ++sub) {
            int sl = cb + sub * 48;
            // ---- loads (all affine; K shared via L1 across the 9 waves) ----
            bf16x8 ksf[3] = {};
            if (quad < 2) {
                ksf[0] = *(const bf16x8*)(ks + (hL + sl + n16) * 16 + quad * 8);
                ksf[1] = *(const bf16x8*)(ks + (hL + sl + 16 + n16) * 16 + quad * 8);
                ksf[2] = *(const bf16x8*)(ks + (hL + sl + 32 + n16) * 16 + quad * 8);
            }
            ushort4 fv[3];
            #pragma unroll
            for (int nt = 0; nt < 3; ++nt)
                fv[nt] = *(const ushort4*)(fsl + (size_t)(sl + nt * 16 + n16) * 16 + quad * 4);
            // ---- QK via MFMA (C init = fc scores) ----
            f32x4 c0 = {bf2f(fv[0].x), bf2f(fv[0].y), bf2f(fv[0].z), bf2f(fv[0].w)};
            f32x4 c1 = {bf2f(fv[1].x), bf2f(fv[1].y), bf2f(fv[1].z), bf2f(fv[1].w)};
            f32x4 c2 = {bf2f(fv[2].x), bf2f(fv[2].y), bf2f(fv[2].z), bf2f(fv[2].w)};
            c0 = __builtin_amdgcn_mfma_f32_16x16x32_bf16(afragQ, ksf[0], c0, 0, 0, 0);
            c1 = __builtin_amdgcn_mfma_f32_16x16x32_bf16(afragQ, ksf[1], c1, 0, 0, 0);
            c2 = __builtin_amdgcn_mfma_f32_16x16x32_bf16(afragQ, ksf[2], c2, 0, 0, 0);
            // ---- online softmax (rows quad*4+r; reduce over n16) ----
            #pragma unroll
            for (int r = 0; r < 4; ++r) {
                float v0 = c0[r], v1 = c1[r], v2 = c2[r];
                float mm = fmaxf(fmaxf(v0, v1), v2);
                mm = fmaxf(mm, __shfl_xor(mm, 1, 16));
                mm = fmaxf(mm, __shfl_xor(mm, 2, 16));
                mm = fmaxf(mm, __shfl_xor(mm, 4, 16));
                mm = fmaxf(mm, __shfl_xor(mm, 8, 16));
                float mn = fmaxf(rm[r], mm);
                float a = __expf(rm[r] - mn);
                float s0 = __expf(v0 - mn), s1 = __expf(v1 - mn), s2 = __expf(v2 - mn);
                float ss = s0 + s1 + s2;
                ss += __shfl_xor(ss, 1, 16);
                ss += __shfl_xor(ss, 2, 16);
                ss += __shfl_xor(ss, 4, 16);
                ss += __shfl_xor(ss, 8, 16);
                rl[r] = rl[r] * a + ss;
                rm[r] = mn;
                acc[0][r] *= a; acc[1][r] *= a; acc[2][r] *= a; acc[3][r] *= a;
                int rw = quad * 4 + r;
                Pp[rw * 56 +      n16] = f2bf(s0);
                Pp[rw * 56 + 16 + n16] = f2bf(s1);
                Pp[rw * 56 + 32 + n16] = f2bf(s2);
            }
            // ---- PV via MFMA: B-frags straight from global vsT ----
            #pragma unroll
            for (int kk = 0; kk < 2; ++kk) {
                // k-slots 48..63 (kk=1, quad>=2) have a ZERO P operand; clamp
                // their B address in-row instead of reading past slot 143.
                int koff = (kk == 0) ? (quad * 8) : (quad < 2 ? 32 + quad * 8 : 0);
                bf16x8 Bv[4];
                #pragma unroll
                for (int ct = 0; ct < 4; ++ct)
                    Bv[ct] = *(const bf16x8*)(vchunk
                        + (size_t)(ct * 16 + n16) * 144 + sub * 48 + koff);
                bf16x8 Ap = {};
                if (kk == 0)
                    Ap = *(const bf16x8*)(Pp + n16 * 56 + quad * 8);
                else if (quad < 2)
                    Ap = *(const bf16x8*)(Pp + n16 * 56 + 32 + quad * 8);
                #pragma unroll
                for (int ct = 0; ct < 4; ++ct)
                    acc[ct] = __builtin_amdgcn_mfma_f32_16x16x32_bf16(Ap, Bv[ct], acc[ct], 0, 0, 0);
            }
        }
    }

    // ---- epilogue: dense writes in sorted order ----
    size_t sp0 = hL + ch0 * 144;
    if (n16 == 0) {
        #pragma unroll
        for (int r = 0; r < 4; ++r)
            bscs[sp0 + mt * 16 + quad * 4 + r] = rm[r] + __logf(rl[r]);
    }
    #pragma unroll
    for (int r = 0; r < 4; ++r) {
        float inv = 1.f / rl[r];
        #pragma unroll
        for (int ct = 0; ct < 4; ++ct)
            rets[(sp0 + mt * 16 + quad * 4 + r) * 64 + ct * 16 + n16] =
                f2bf(acc[ct][r] * inv);
    }
}

// ---------------- K5: softmax over rounds + residual, NCHW output ----------------
// Reads sorted rets/bscs through the undo permutation (scattered 128B-row reads).
__global__ __launch_bounds__(256) void k_final(
    const unsigned short* __restrict__ rets, const float* __restrict__ bscs,
    const int* __restrict__ undo, const float* __restrict__ x,
    float* __restrict__ out)
{
    __shared__ float pr[4][64];
    __shared__ int us[4][64];
    __shared__ float accl[64 * 65];
    int b = blockIdx.x, n = b / 144;
    int t0 = (b % 144) * 64;
    int tid = threadIdx.x;
    {
        int h = tid >> 6, tt = tid & 63;
        us[h][tt] = undo[((size_t)n * 4 + h) * LL + t0 + tt];
    }
    __syncthreads();
    if (tid < 64) {
        float b0 = bscs[((size_t)n * 4 + 0) * LL + us[0][tid]];
        float b1 = bscs[((size_t)n * 4 + 1) * LL + us[1][tid]];
        float b2 = bscs[((size_t)n * 4 + 2) * LL + us[2][tid]];
        float b3 = bscs[((size_t)n * 4 + 3) * LL + us[3][tid]];
        float mx = fmaxf(fmaxf(b0, b1), fmaxf(b2, b3));
        float e0 = __expf(b0-mx), e1 = __expf(b1-mx), e2 = __expf(b2-mx), e3 = __expf(b3-mx);
        float inv = 1.f / (e0 + e1 + e2 + e3);
        pr[0][tid] = e0*inv; pr[1][tid] = e1*inv; pr[2][tid] = e2*inv; pr[3][tid] = e3*inv;
    }
    __syncthreads();
    int cc = tid & 63, tt4 = tid >> 6;
    #pragma unroll
    for (int q = 0; q < 16; ++q) {
        int tt = tt4 + 4*q;
        float v = 0.f;
        #pragma unroll
        for (int h2 = 0; h2 < 4; ++h2)
            v += bf2f(rets[(((size_t)n*4 + h2)*LL + us[h2][tt])*64 + cc]) * pr[h2][tt];
        accl[cc*65 + tt] = v;
    }
    __syncthreads();
    int tt = tid & 63, c4 = tid >> 6;
    #pragma unroll
    for (int q = 0; q < 16; ++q) {
        int ch = c4 + 4*q;
        size_t o = ((size_t)n*64 + ch)*LL + t0 + tt;
        out[o] = accl[ch*65 + tt] + x[o];   // RES_SCALE = 1.0
    }
}

// ---------------- launcher ----------------
extern "C" void kernel_launch(void* const* d_in, const int* in_sizes, int n_in,
                              void* d_out, int out_size, void* d_ws, size_t ws_size,
                              hipStream_t stream)
{
    const float* x    = (const float*)d_in[0];
    const float* rot  = (const float*)d_in[1];
    const float* wm   = (const float*)d_in[2];
    const float* bm   = (const float*)d_in[3];
    const float* wa   = (const float*)d_in[4];
    const float* ba   = (const float*)d_in[5];
    const float* wf   = (const float*)d_in[6];
    const float* bf   = (const float*)d_in[7];
    const float* fc1w = (const float*)d_in[8];
    const float* fc1b = (const float*)d_in[9];
    const float* fc2w = (const float*)d_in[10];
    const float* fc2b = (const float*)d_in[11];
    float* out = (float*)d_out;

    char* ws = (char*)d_ws;
    // pre-sort stage
    unsigned short* xeb  = (unsigned short*)(ws + 0);         // 2*9216*16 bf16
    unsigned short* yeb  = (unsigned short*)(ws + 589824);    // 2*9216*64 bf16
    unsigned short* xnb  = (unsigned short*)(ws + 2949120);   // 2*9216*16 bf16
    unsigned short* re2b = (unsigned short*)(ws + 3538944);   // 2*9216*144 bf16
    unsigned short* w1bf = (unsigned short*)(ws + 8847360);   // 144*64 bf16
    unsigned short* w2bf = (unsigned short*)(ws + 8865792);   // 144*160 bf16
    unsigned short* wpak = (unsigned short*)(ws + 8911872);   // 128*576 bf16
    unsigned char* codes = (unsigned char*)(ws + 9059328);    // 2*36864 u8
    int* hist            = (int*)(ws + 9133056);              // 2*256*144 i32
    int* idxb            = (int*)(ws + 9427968);              // 2*36864 i32 -> 9,575,424
    // post-sort stage. rets/bscs ALIAS the pre-sort region (xeb..idxb), which is
    // dead once k_gather has run (k_attn reads only qs/ks/vsT/fst).
    unsigned short* rets = (unsigned short*)(ws + 0);         // 8*9216*64 bf16 (9,437,184)
    float* bscs          = (float*)(ws + 9437184);            // 8*9216 f32
    unsigned short* qs   = (unsigned short*)(ws + 9732096);   // 8*9216*16 bf16
    unsigned short* ks   = (unsigned short*)(ws + 12091392);  // 8*9216*16 bf16
    unsigned short* vsT  = (unsigned short*)(ws + 14450688);  // 512*64*144 bf16 (9.4 MB)
    unsigned short* fst  = (unsigned short*)(ws + 23887872);  // 72*9216*16 bf16 (21.2 MB)
    int* undo            = (int*)(ws + 45121536);             // 8*9216 i32 (end 45,416,448)

    k_front    <<<576, 256, 0, stream>>>(x, wm, bm, rot, xeb, xnb, codes,
                                         fc1w, fc2w, wa, wf, w1bf, w2bf, wpak);
    k_convbf_fc<<<672, 256, 0, stream>>>(x, wpak, ba, bf, w1bf, fc1b, w2bf, fc2b,
                                         yeb, re2b, codes, hist);
    k_scan     <<<2,    256, 0, stream>>>(hist);
    k_place    <<<288,  256, 0, stream>>>(codes, hist, idxb);
    k_gather   <<<512,  256, 0, stream>>>(idxb, xeb, xnb, yeb, re2b,
                                          qs, ks, vsT, fst, undo);
    k_attn     <<<512,  576, 0, stream>>>(qs, ks, vsT, fst, rets, bscs);
    k_final    <<<288,  256, 0, stream>>>(rets, bscs, undo, x, out);
}